// Round 4
// baseline (340.897 us; speedup 1.0000x reference)
//
#include <hip/hip_runtime.h>
#include <hip/hip_bf16.h>
#include <cstdint>
#include <cstddef>

#define TPB 256

typedef __attribute__((ext_vector_type(8))) short bf16x8;
typedef __attribute__((ext_vector_type(8))) unsigned short ushort8;
typedef __attribute__((ext_vector_type(4))) float f32x4;
typedef __attribute__((ext_vector_type(8))) float f32x8;

static __device__ __forceinline__ float bf2f(unsigned short u) {
  union { unsigned int i; float f; } c;
  c.i = ((unsigned int)u) << 16;
  return c.f;
}

// ---------------------------------------------------------------------------
// Edge dtype detection: int64 edge values < 10000 -> all odd 32-bit words zero
// ---------------------------------------------------------------------------
__global__ void detect_kernel(const unsigned int* __restrict__ w, int* __restrict__ flag) {
  __shared__ int any32;
  if (threadIdx.x == 0) any32 = 0;
  __syncthreads();
  for (int i = threadIdx.x; i < 1024; i += TPB)
    if (w[2 * i + 1] != 0u) any32 = 1;
  __syncthreads();
  if (threadIdx.x == 0) *flag = any32;   // 1 -> int32 data, 0 -> int64 data
}

__global__ void decode_kernel(const void* __restrict__ raw, const int* __restrict__ flag,
                              int* __restrict__ src, int* __restrict__ dst, int E, int n) {
  int i = blockIdx.x * TPB + threadIdx.x;
  int tot = E + n;
  if (i >= tot) return;
  if (i < E) {
    if (*flag) {
      const int* p = (const int*)raw;
      src[i] = p[i];
      dst[i] = p[E + i];
    } else {
      const long long* p = (const long long*)raw;
      src[i] = (int)p[i];
      dst[i] = (int)p[E + i];
    }
  } else {                 // self loops appended
    src[i] = i - E;
    dst[i] = i - E;
  }
}

// ---------------------------------------------------------------------------
// CSR build: count -> scan -> fill
// ---------------------------------------------------------------------------
__global__ void count_kernel(const int* __restrict__ dst, int* __restrict__ counts, int etot) {
  int i = blockIdx.x * TPB + threadIdx.x;
  if (i < etot) atomicAdd(&counts[dst[i]], 1);
}

__global__ void scan_kernel(const int* __restrict__ counts, int* __restrict__ row_ptr, int n) {
  __shared__ int part[TPB];
  int tid = threadIdx.x;
  int chunk = (n + TPB - 1) / TPB;
  int begin = tid * chunk;
  int end = begin + chunk; if (end > n) end = n;
  int s = 0;
  for (int i = begin; i < end && i < n; i++) s += counts[i];
  part[tid] = s;
  __syncthreads();
  for (int off = 1; off < TPB; off <<= 1) {
    int v = (tid >= off) ? part[tid - off] : 0;
    __syncthreads();
    part[tid] += v;
    __syncthreads();
  }
  int base = (tid == 0) ? 0 : part[tid - 1];
  for (int i = begin; i < end && i < n; i++) { row_ptr[i] = base; base += counts[i]; }
  if (tid == TPB - 1) row_ptr[n] = base;
}

__global__ void fill_kernel(const int* __restrict__ src, const int* __restrict__ dst,
                            const int* __restrict__ row_ptr, int* __restrict__ fill,
                            int* __restrict__ sorted_src, int etot) {
  int i = blockIdx.x * TPB + threadIdx.x;
  if (i >= etot) return;
  int d = dst[i];
  int pos = row_ptr[d] + atomicAdd(&fill[d], 1);
  sorted_src[pos] = src[i];
}

// ---------------------------------------------------------------------------
// fp32 -> bf16 convert (linear)
// ---------------------------------------------------------------------------
__global__ void f32_to_bf16_kernel(const float* __restrict__ in, __hip_bfloat16* __restrict__ out, int n) {
  int i = blockIdx.x * TPB + threadIdx.x;
  if (i < n) out[i] = __float2bfloat16(in[i]);
}

// fp32 [K][N] -> bf16 transposed [N][K]
__global__ void f32_to_bf16_T_kernel(const float* __restrict__ in, __hip_bfloat16* __restrict__ out,
                                     int K, int N) {
  __shared__ float tile[32][33];
  const int k0 = blockIdx.x * 32, n0 = blockIdx.y * 32;
  const int tx = threadIdx.x & 31, ty = threadIdx.x >> 5;   // 32 x 8
  for (int r = ty; r < 32; r += 8) {
    int k = k0 + r, n = n0 + tx;
    tile[r][tx] = (k < K && n < N) ? in[(size_t)k * N + n] : 0.f;
  }
  __syncthreads();
  for (int r = ty; r < 32; r += 8) {
    int n = n0 + r, k = k0 + tx;
    if (n < N && k < K) out[(size_t)n * K + k] = __float2bfloat16(tile[tx][r]);
  }
}

// ---------------------------------------------------------------------------
// bf16 MFMA GEMM with pre-transposed B: C[M,N] = A[M,K] @ Bt[N,K]^T (+bias).
// Tile 64(M) x 128(N), BK=32, 4 waves, mfma_f32_16x16x32_bf16.
// ---------------------------------------------------------------------------
__global__ __launch_bounds__(256) void gemm_bf16t_kernel(
    const short* __restrict__ A, const short* __restrict__ Bt,
    const float* __restrict__ bias, float* __restrict__ C,
    __hip_bfloat16* __restrict__ Cb, int M, int N, int K) {
  __shared__ short As[64][40];    // [row][k], 80B row stride
  __shared__ short Bs[128][40];   // [col][k]

  const int tid = threadIdx.x;
  const int lane = tid & 63;
  const int w = tid >> 6;
  const int bm = blockIdx.x * 64;
  const int bn = blockIdx.y * 128;

  f32x4 acc[8];
#pragma unroll
  for (int nt = 0; nt < 8; nt++) acc[nt] = (f32x4){0.f, 0.f, 0.f, 0.f};

  const int arow = tid >> 2;          // 0..63
  const int akk = (tid & 3) << 3;     // 0,8,16,24
  const int brow = tid >> 1;          // 0..127
  const int bkk = (tid & 1) << 4;     // 0,16

  for (int k0 = 0; k0 < K; k0 += 32) {
    // stage A (64 x 32): one 16B load per thread
    {
      int gr = bm + arow;
      if (gr < M) {
        *(bf16x8*)&As[arow][akk] = *(const bf16x8*)&A[(size_t)gr * K + k0 + akk];
      } else {
        bf16x8 z = {0, 0, 0, 0, 0, 0, 0, 0};
        *(bf16x8*)&As[arow][akk] = z;
      }
    }
    // stage B (128 cols x 32 k): two 16B loads per thread from transposed Bt
    {
      int gbn = bn + brow;
      if (gbn < N) {
        const short* bp = &Bt[(size_t)gbn * K + k0 + bkk];
        *(bf16x8*)&Bs[brow][bkk]     = *(const bf16x8*)bp;
        *(bf16x8*)&Bs[brow][bkk + 8] = *(const bf16x8*)(bp + 8);
      } else {
        bf16x8 z = {0, 0, 0, 0, 0, 0, 0, 0};
        *(bf16x8*)&Bs[brow][bkk] = z;
        *(bf16x8*)&Bs[brow][bkk + 8] = z;
      }
    }
    __syncthreads();

    bf16x8 a = *(const bf16x8*)&As[w * 16 + (lane & 15)][(lane >> 4) * 8];
#pragma unroll
    for (int nt = 0; nt < 8; nt++) {
      bf16x8 b = *(const bf16x8*)&Bs[nt * 16 + (lane & 15)][(lane >> 4) * 8];
      acc[nt] = __builtin_amdgcn_mfma_f32_16x16x32_bf16(a, b, acc[nt], 0, 0, 0);
    }
    __syncthreads();
  }

#pragma unroll
  for (int nt = 0; nt < 8; nt++) {
    int gc = bn + nt * 16 + (lane & 15);
    if (gc >= N) continue;
    float bv = bias ? bias[gc] : 0.f;
#pragma unroll
    for (int q = 0; q < 4; q++) {
      int gr = bm + w * 16 + (lane >> 4) * 4 + q;
      if (gr < M) {
        float val = acc[nt][q] + bv;
        if (C) C[(size_t)gr * N + gc] = val;
        if (Cb) Cb[(size_t)gr * N + gc] = __float2bfloat16(val);
      }
    }
  }
}

// ---------------------------------------------------------------------------
// attention coefficients, H=8 C=128, bf16 input g: block 256, one node/block
// ---------------------------------------------------------------------------
__global__ void attn_coeff8_kernel(const unsigned short* __restrict__ gb,
                                   const float* __restrict__ asrc,
                                   const float* __restrict__ adst,
                                   float* __restrict__ es, float* __restrict__ ed) {
  const int v = blockIdx.x;
  const int tid = threadIdx.x;
  ushort4 gu = *(const ushort4*)&gb[(size_t)v * 1024 + 4 * tid];
  float4 av = *(const float4*)&asrc[4 * tid];
  float4 dv = *(const float4*)&adst[4 * tid];
  float gx = bf2f(gu.x), gy = bf2f(gu.y), gz = bf2f(gu.z), gw = bf2f(gu.w);
  float p1 = gx * av.x + gy * av.y + gz * av.z + gw * av.w;
  float p2 = gx * dv.x + gy * dv.y + gz * dv.z + gw * dv.w;
#pragma unroll
  for (int off = 16; off > 0; off >>= 1) {
    p1 += __shfl_down(p1, off);
    p2 += __shfl_down(p2, off);
  }
  if ((tid & 31) == 0) {
    es[(size_t)v * 8 + (tid >> 5)] = p1;
    ed[(size_t)v * 8 + (tid >> 5)] = p2;
  }
}

// f32 variant for layer 2 (H=1, C=64)
template <int H, int C>
__global__ void attn_coeff_kernel(const float* __restrict__ g,
                                  const float* __restrict__ asrc,
                                  const float* __restrict__ adst,
                                  float* __restrict__ es, float* __restrict__ ed) {
  int v = blockIdx.x;
  int tid = threadIdx.x;
  __shared__ float rs[2], rd[2];
  const float* grow = g + (size_t)v * (H * C);
  for (int h = 0; h < H; ++h) {
    float gv = grow[h * C + tid];
    float p1 = gv * asrc[h * C + tid];
    float p2 = gv * adst[h * C + tid];
#pragma unroll
    for (int off = 32; off > 0; off >>= 1) {
      p1 += __shfl_down(p1, off);
      p2 += __shfl_down(p2, off);
    }
    if ((tid & 63) == 0) { rs[tid >> 6] = p1; rd[tid >> 6] = p2; }
    __syncthreads();
    if (tid == 0) {
      float s1 = rs[0], s2 = rd[0];
      if (C > 64) { s1 += rs[1]; s2 += rd[1]; }
      es[(size_t)v * H + h] = s1;
      ed[(size_t)v * H + h] = s2;
    }
    __syncthreads();
  }
}

// ---------------------------------------------------------------------------
// Per-dst softmax + aggregation, H=8 C=128, bf16 g.
// Fast path (deg<=128): alpha computed ONCE into LDS (single es gather),
// max/denom reduced over LDS. Gather: 128 lanes/row, 16B ushort8 loads,
// 2 edges in parallel, 4-deep unroll.
// ---------------------------------------------------------------------------
__global__ __launch_bounds__(256) void gat_aggregate8_kernel(
    const int* __restrict__ row_ptr, const int* __restrict__ srcs,
    const unsigned short* __restrict__ gb, const float* __restrict__ es,
    const float* __restrict__ ed, const float* __restrict__ bias,
    float* __restrict__ out) {
  constexpr int T = 256, H = 8, HC = 1024, CAP = 128;
  const int v = blockIdx.x;
  const int tid = threadIdx.x;
  const int h = tid & 7;
  const int jj = tid >> 3;      // 32 edge-groups for LDS reductions

  __shared__ float alds[CAP * H];   // alpha -> p -> w
  __shared__ int slds[CAP];
  __shared__ float red[T];
  __shared__ float mh[H], invd[H], edv8[H];
  __shared__ float red8[T][8];

  const int begin = row_ptr[v];
  const int deg = row_ptr[v + 1] - begin;

  if (tid < H) edv8[tid] = ed[(size_t)v * H + tid];
  __syncthreads();

  const int half = tid >> 7;        // 0/1: which edge parity
  const int t128 = tid & 127;
  const int c0 = t128 * 8;          // channel offset within 1024
  const int hh = t128 >> 4;         // head for weight lookup

  f32x8 acc = {0.f, 0.f, 0.f, 0.f, 0.f, 0.f, 0.f, 0.f};

  auto gather = [&](int cnt) {
    int j = half;
    for (; j + 6 < cnt; j += 8) {
      int s0 = slds[j], s1 = slds[j + 2], s2 = slds[j + 4], s3 = slds[j + 6];
      float w0 = alds[j * 8 + hh], w1 = alds[(j + 2) * 8 + hh];
      float w2 = alds[(j + 4) * 8 + hh], w3 = alds[(j + 6) * 8 + hh];
      ushort8 u0 = *(const ushort8*)&gb[(size_t)s0 * HC + c0];
      ushort8 u1 = *(const ushort8*)&gb[(size_t)s1 * HC + c0];
      ushort8 u2 = *(const ushort8*)&gb[(size_t)s2 * HC + c0];
      ushort8 u3 = *(const ushort8*)&gb[(size_t)s3 * HC + c0];
#pragma unroll
      for (int k = 0; k < 8; k++)
        acc[k] += w0 * bf2f(u0[k]) + w1 * bf2f(u1[k]) + w2 * bf2f(u2[k]) + w3 * bf2f(u3[k]);
    }
    for (; j < cnt; j += 2) {
      int s = slds[j];
      float wv = alds[j * 8 + hh];
      ushort8 u = *(const ushort8*)&gb[(size_t)s * HC + c0];
#pragma unroll
      for (int k = 0; k < 8; k++) acc[k] += wv * bf2f(u[k]);
    }
  };

  if (deg <= CAP) {
    // single es gather -> alpha in LDS
    for (int idx = tid; idx < deg * 8; idx += T) {
      int j = idx >> 3, hx = idx & 7;
      int s = srcs[begin + j];
      if (hx == 0) slds[j] = s;
      float a = es[(size_t)s * 8 + hx] + edv8[hx];
      alds[idx] = a > 0.f ? a : 0.2f * a;
    }
    __syncthreads();
    // per-head max over LDS
    float pm = -1e30f;
    for (int j = jj; j < deg; j += 32) pm = fmaxf(pm, alds[j * 8 + h]);
    red[tid] = pm;
    __syncthreads();
    if (tid < H) {
      float m = -1e30f;
      for (int g2 = 0; g2 < 32; g2++) m = fmaxf(m, red[g2 * 8 + tid]);
      mh[tid] = m;
    }
    __syncthreads();
    // exp in place + denom
    float ps = 0.f;
    float m = mh[h];
    for (int j = jj; j < deg; j += 32) {
      float p = __expf(alds[j * 8 + h] - m);
      alds[j * 8 + h] = p;
      ps += p;
    }
    red[tid] = ps;
    __syncthreads();
    if (tid < H) {
      float d = 0.f;
      for (int g2 = 0; g2 < 32; g2++) d += red[g2 * 8 + tid];
      invd[tid] = 1.0f / (d + 1e-16f);
    }
    __syncthreads();
    // scale to final weights
    for (int idx = tid; idx < deg * 8; idx += T) alds[idx] *= invd[idx & 7];
    __syncthreads();
    gather(deg);
  } else {
    // slow path: recompute passes for max/denom, then chunked weight+gather
    float pm = -1e30f;
    for (int j = jj; j < deg; j += 32) {
      int s = srcs[begin + j];
      float a = es[(size_t)s * 8 + h] + edv8[h];
      a = a > 0.f ? a : 0.2f * a;
      pm = fmaxf(pm, a);
    }
    red[tid] = pm;
    __syncthreads();
    if (tid < H) {
      float m = -1e30f;
      for (int g2 = 0; g2 < 32; g2++) m = fmaxf(m, red[g2 * 8 + tid]);
      mh[tid] = m;
    }
    __syncthreads();
    float ps = 0.f;
    for (int j = jj; j < deg; j += 32) {
      int s = srcs[begin + j];
      float a = es[(size_t)s * 8 + h] + edv8[h];
      a = a > 0.f ? a : 0.2f * a;
      ps += __expf(a - mh[h]);
    }
    red[tid] = ps;
    __syncthreads();
    if (tid < H) {
      float d = 0.f;
      for (int g2 = 0; g2 < 32; g2++) d += red[g2 * 8 + tid];
      invd[tid] = 1.0f / (d + 1e-16f);
    }
    for (int base = 0; base < deg; base += CAP) {
      int cnt = deg - base; if (cnt > CAP) cnt = CAP;
      __syncthreads();
      for (int idx = tid; idx < cnt * 8; idx += T) {
        int j = idx >> 3, hx = idx & 7;
        int s = srcs[begin + base + j];
        if (hx == 0) slds[j] = s;
        float a = es[(size_t)s * 8 + hx] + edv8[hx];
        a = a > 0.f ? a : 0.2f * a;
        alds[idx] = __expf(a - mh[hx]) * invd[hx];
      }
      __syncthreads();
      gather(cnt);
    }
  }

  // epilogue: reduce 16 thread-groups (2 halves x 8 heads), head-mean + bias
  __syncthreads();
#pragma unroll
  for (int k = 0; k < 8; k++) red8[tid][k] = acc[k];
  __syncthreads();
  if (tid < 16) {
    float o[8] = {0.f, 0.f, 0.f, 0.f, 0.f, 0.f, 0.f, 0.f};
    for (int q = 0; q < 16; q++) {
      const float* r = red8[q * 16 + tid];
#pragma unroll
      for (int k = 0; k < 8; k++) o[k] += r[k];
    }
    int cb = tid * 8;
#pragma unroll
    for (int k = 0; k < 8; k++)
      out[(size_t)v * 128 + cb + k] = o[k] * 0.125f + bias[cb + k];
  }
}

// ---------------------------------------------------------------------------
// Layer-2 aggregation (H=1, C=64): one WAVE per dst node, 4 nodes/block.
// ---------------------------------------------------------------------------
__global__ __launch_bounds__(256) void gat_aggregate1_kernel(
    const int* __restrict__ row_ptr, const int* __restrict__ srcs,
    const float* __restrict__ g, const float* __restrict__ es,
    const float* __restrict__ ed, const float* __restrict__ bias,
    float* __restrict__ out, int n) {
  const int wave = threadIdx.x >> 6;
  const int lane = threadIdx.x & 63;
  const int v = blockIdx.x * 4 + wave;
  if (v >= n) return;

  const int begin = row_ptr[v];
  const int deg = row_ptr[v + 1] - begin;
  const float edv = ed[v];

  float pm = -1e30f;
  for (int j = lane; j < deg; j += 64) {
    float a = es[srcs[begin + j]] + edv;
    a = a > 0.f ? a : 0.2f * a;
    pm = fmaxf(pm, a);
  }
#pragma unroll
  for (int off = 32; off > 0; off >>= 1) pm = fmaxf(pm, __shfl_xor(pm, off));

  float ps = 0.f;
  for (int j = lane; j < deg; j += 64) {
    float a = es[srcs[begin + j]] + edv;
    a = a > 0.f ? a : 0.2f * a;
    ps += expf(a - pm);
  }
#pragma unroll
  for (int off = 32; off > 0; off >>= 1) ps += __shfl_xor(ps, off);
  const float invd = 1.0f / (ps + 1e-16f);

  float acc = 0.f;
  for (int base = 0; base < deg; base += 64) {
    int cnt = deg - base; if (cnt > 64) cnt = 64;
    int sv = 0; float wv = 0.f;
    if (lane < cnt) {
      sv = srcs[begin + base + lane];
      float a = es[sv] + edv;
      a = a > 0.f ? a : 0.2f * a;
      wv = expf(a - pm) * invd;
    }
    for (int j = 0; j < cnt; j++) {
      int s = __shfl(sv, j);
      float wgt = __shfl(wv, j);
      acc += wgt * g[(size_t)s * 64 + lane];
    }
  }
  out[(size_t)v * 64 + lane] = acc + bias[lane];
}

// ---------------------------------------------------------------------------
// BN column stats
// ---------------------------------------------------------------------------
template <int C>
__global__ void bn_stats_kernel(const float* __restrict__ x, int n, float* __restrict__ sums) {
  constexpr int T = 256;
  constexpr int RPI = T / C;
  constexpr int ITER = 64;
  constexpr int ROWS = RPI * ITER;
  int c = threadIdx.x % C;
  int r0 = threadIdx.x / C;
  int rowBase = blockIdx.x * ROWS;
  float s = 0.f, q = 0.f;
  for (int it = 0; it < ITER; ++it) {
    int r = rowBase + it * RPI + r0;
    if (r < n) {
      float v = x[(size_t)r * C + c];
      s += v; q += v * v;
    }
  }
  __shared__ float ls[T], lq[T];
  ls[threadIdx.x] = s; lq[threadIdx.x] = q;
  __syncthreads();
  if (threadIdx.x < C) {
    float ts = 0.f, tq = 0.f;
    for (int r = 0; r < RPI; ++r) { ts += ls[c + r * C]; tq += lq[c + r * C]; }
    atomicAdd(&sums[c], ts);
    atomicAdd(&sums[C + c], tq);
  }
}

// ---------------------------------------------------------------------------
// out = elu(bn(x)) + res ; optional bf16 copy of out
// ---------------------------------------------------------------------------
template <int C>
__global__ void bn_elu_res_kernel(const float* __restrict__ x, const float* __restrict__ sums,
                                  const float* __restrict__ gamma, const float* __restrict__ beta,
                                  const float* __restrict__ res, float* __restrict__ out,
                                  __hip_bfloat16* __restrict__ outb, int n) {
  int i = blockIdx.x * TPB + threadIdx.x;
  if (i >= n * C) return;
  int c = i % C;
  float inv_n = 1.0f / (float)n;
  float mu = sums[c] * inv_n;
  float var = sums[C + c] * inv_n - mu * mu;
  float y = (x[i] - mu) * rsqrtf(var + 1e-5f) * gamma[c] + beta[c];
  y = y > 0.f ? y : expm1f(y);
  y += res[i];
  out[i] = y;
  if (outb) outb[i] = __float2bfloat16(y);
}

// ---------------------------------------------------------------------------
// host launch
// ---------------------------------------------------------------------------
extern "C" void kernel_launch(void* const* d_in, const int* in_sizes, int n_in,
                              void* d_out, int out_size, void* d_ws, size_t ws_size,
                              hipStream_t stream) {
  const float* x   = (const float*)d_in[0];
  const void*  ei  = d_in[1];
  const float* Wp  = (const float*)d_in[2];
  const float* bp  = (const float*)d_in[3];
  const float* W0  = (const float*)d_in[4];
  const float* as0 = (const float*)d_in[5];
  const float* ad0 = (const float*)d_in[6];
  const float* b0  = (const float*)d_in[7];
  const float* g0  = (const float*)d_in[8];
  const float* be0 = (const float*)d_in[9];
  const float* W1  = (const float*)d_in[10];
  const float* as1 = (const float*)d_in[11];
  const float* ad1 = (const float*)d_in[12];
  const float* b1  = (const float*)d_in[13];
  const float* g1  = (const float*)d_in[14];
  const float* be1 = (const float*)d_in[15];
  const float* W2  = (const float*)d_in[16];
  const float* as2 = (const float*)d_in[17];
  const float* ad2 = (const float*)d_in[18];
  const float* b2  = (const float*)d_in[19];
  const float* g2  = (const float*)d_in[20];
  const float* be2 = (const float*)d_in[21];
  const float* Wr  = (const float*)d_in[22];
  const float* br  = (const float*)d_in[23];

  const int N = in_sizes[0] / 64;       // 10000
  const int E = in_sizes[1] / 2;        // 160000
  const int ETOT = E + N;

  char* wsp = (char*)d_ws;
  size_t off = 0;
  auto alloc = [&](size_t bytes) -> void* {
    void* p = wsp + off;
    off += (bytes + 255) & ~(size_t)255;
    return p;
  };
  int*   flag    = (int*)alloc(4);
  int*   e_src   = (int*)alloc((size_t)ETOT * 4);
  int*   e_dst   = (int*)alloc((size_t)ETOT * 4);
  int*   counts  = (int*)alloc((size_t)N * 4);
  int*   fillc   = (int*)alloc((size_t)N * 4);
  int*   row_ptr = (int*)alloc((size_t)(N + 1) * 4);
  int*   s_src   = (int*)alloc((size_t)ETOT * 4);
  float* hA      = (float*)alloc((size_t)N * 128 * 4);
  float* hB      = (float*)alloc((size_t)N * 128 * 4);
  float* gbuf    = (float*)alloc((size_t)N * 64 * 4);       // layer-2 g (f32)
  float* gat     = (float*)alloc((size_t)N * 128 * 4);
  float* es      = (float*)alloc((size_t)N * 8 * 4);
  float* ed      = (float*)alloc((size_t)N * 8 * 4);
  float* bnsum   = (float*)alloc(2 * 128 * 4);
  __hip_bfloat16* gbufb = (__hip_bfloat16*)alloc((size_t)N * 1024 * 2);  // big-layer g (bf16)
  __hip_bfloat16* xb  = (__hip_bfloat16*)alloc((size_t)N * 64 * 2);
  __hip_bfloat16* hAb = (__hip_bfloat16*)alloc((size_t)N * 128 * 2);
  __hip_bfloat16* hBb = (__hip_bfloat16*)alloc((size_t)N * 128 * 2);
  __hip_bfloat16* WpT = (__hip_bfloat16*)alloc((size_t)128 * 64 * 2);   // [128][64]
  __hip_bfloat16* W0T = (__hip_bfloat16*)alloc((size_t)1024 * 128 * 2); // [1024][128]
  __hip_bfloat16* W1T = (__hip_bfloat16*)alloc((size_t)1024 * 128 * 2);
  __hip_bfloat16* W2T = (__hip_bfloat16*)alloc((size_t)64 * 128 * 2);
  __hip_bfloat16* WrT = (__hip_bfloat16*)alloc((size_t)64 * 128 * 2);

  const int egrid = (ETOT + TPB - 1) / TPB;
  const int mgrid = (N + 63) / 64;      // 157
  auto cgrid = [](int n) { return (n + TPB - 1) / TPB; };

  // ---- graph prep ----
  detect_kernel<<<1, TPB, 0, stream>>>((const unsigned int*)ei, flag);
  decode_kernel<<<egrid, TPB, 0, stream>>>(ei, flag, e_src, e_dst, E, N);
  hipMemsetAsync(counts, 0, (size_t)N * 4, stream);
  hipMemsetAsync(fillc, 0, (size_t)N * 4, stream);
  count_kernel<<<egrid, TPB, 0, stream>>>(e_dst, counts, ETOT);
  scan_kernel<<<1, TPB, 0, stream>>>(counts, row_ptr, N);
  fill_kernel<<<egrid, TPB, 0, stream>>>(e_src, e_dst, row_ptr, fillc, s_src, ETOT);

  // ---- weight / input conversions (weights transposed for GEMM B) ----
  f32_to_bf16_kernel<<<cgrid(N * 64), TPB, 0, stream>>>(x, xb, N * 64);
  f32_to_bf16_T_kernel<<<dim3(2, 4), 256, 0, stream>>>(Wp, WpT, 64, 128);
  f32_to_bf16_T_kernel<<<dim3(4, 32), 256, 0, stream>>>(W0, W0T, 128, 1024);
  f32_to_bf16_T_kernel<<<dim3(4, 32), 256, 0, stream>>>(W1, W1T, 128, 1024);
  f32_to_bf16_T_kernel<<<dim3(4, 2), 256, 0, stream>>>(W2, W2T, 128, 64);
  f32_to_bf16_T_kernel<<<dim3(4, 2), 256, 0, stream>>>(Wr, WrT, 128, 64);

  // ---- projection: hA = x @ Wp + bp (also bf16 copy hAb) ----
  gemm_bf16t_kernel<<<dim3(mgrid, 1), 256, 0, stream>>>(
      (const short*)xb, (const short*)WpT, bp, hA, hAb, N, 128, 64);

  // ---- layer 0 (g written bf16-only) ----
  gemm_bf16t_kernel<<<dim3(mgrid, 8), 256, 0, stream>>>(
      (const short*)hAb, (const short*)W0T, nullptr, nullptr, gbufb, N, 1024, 128);
  attn_coeff8_kernel<<<N, 256, 0, stream>>>((const unsigned short*)gbufb, as0, ad0, es, ed);
  gat_aggregate8_kernel<<<N, 256, 0, stream>>>(row_ptr, s_src, (const unsigned short*)gbufb, es, ed, b0, gat);
  hipMemsetAsync(bnsum, 0, 2 * 128 * 4, stream);
  bn_stats_kernel<128><<<(N + 127) / 128, 256, 0, stream>>>(gat, N, bnsum);
  bn_elu_res_kernel<128><<<cgrid(N * 128), TPB, 0, stream>>>(gat, bnsum, g0, be0, hA, hB, hBb, N);

  // ---- layer 1 ----
  gemm_bf16t_kernel<<<dim3(mgrid, 8), 256, 0, stream>>>(
      (const short*)hBb, (const short*)W1T, nullptr, nullptr, gbufb, N, 1024, 128);
  attn_coeff8_kernel<<<N, 256, 0, stream>>>((const unsigned short*)gbufb, as1, ad1, es, ed);
  gat_aggregate8_kernel<<<N, 256, 0, stream>>>(row_ptr, s_src, (const unsigned short*)gbufb, es, ed, b1, gat);
  hipMemsetAsync(bnsum, 0, 2 * 128 * 4, stream);
  bn_stats_kernel<128><<<(N + 127) / 128, 256, 0, stream>>>(gat, N, bnsum);
  bn_elu_res_kernel<128><<<cgrid(N * 128), TPB, 0, stream>>>(gat, bnsum, g1, be1, hB, hA, hAb, N);

  // ---- layer 2 (H=1, C=64) ----
  gemm_bf16t_kernel<<<dim3(mgrid, 1), 256, 0, stream>>>(
      (const short*)hAb, (const short*)WrT, br, hB, nullptr, N, 64, 128);    // hr
  gemm_bf16t_kernel<<<dim3(mgrid, 1), 256, 0, stream>>>(
      (const short*)hAb, (const short*)W2T, nullptr, gbuf, nullptr, N, 64, 128);
  attn_coeff_kernel<1, 64><<<N, 64, 0, stream>>>(gbuf, as2, ad2, es, ed);
  gat_aggregate1_kernel<<<(N + 3) / 4, 256, 0, stream>>>(row_ptr, s_src, gbuf, es, ed, b2, gat, N);
  hipMemsetAsync(bnsum, 0, 2 * 64 * 4, stream);
  bn_stats_kernel<64><<<(N + 255) / 256, 256, 0, stream>>>(gat, N, bnsum);
  bn_elu_res_kernel<64><<<cgrid(N * 64), TPB, 0, stream>>>(gat, bnsum, g2, be2, hB, (float*)d_out, nullptr, N);
}

// Round 5
// 336.042 us; speedup vs baseline: 1.0144x; 1.0144x over previous
//
#include <hip/hip_runtime.h>
#include <hip/hip_bf16.h>
#include <cstdint>
#include <cstddef>

#define TPB 256

typedef __attribute__((ext_vector_type(8))) short bf16x8;
typedef __attribute__((ext_vector_type(8))) unsigned short ushort8;
typedef __attribute__((ext_vector_type(4))) float f32x4;

static __device__ __forceinline__ float bf2f(unsigned short u) {
  union { unsigned int i; float f; } c;
  c.i = ((unsigned int)u) << 16;
  return c.f;
}

// ---------------------------------------------------------------------------
// Edge dtype detection: int64 edge values < 10000 -> all odd 32-bit words zero
// ---------------------------------------------------------------------------
__global__ void detect_kernel(const unsigned int* __restrict__ w, int* __restrict__ flag) {
  __shared__ int any32;
  if (threadIdx.x == 0) any32 = 0;
  __syncthreads();
  for (int i = threadIdx.x; i < 1024; i += TPB)
    if (w[2 * i + 1] != 0u) any32 = 1;
  __syncthreads();
  if (threadIdx.x == 0) *flag = any32;   // 1 -> int32 data, 0 -> int64 data
}

__global__ void decode_kernel(const void* __restrict__ raw, const int* __restrict__ flag,
                              int* __restrict__ src, int* __restrict__ dst, int E, int n) {
  int i = blockIdx.x * TPB + threadIdx.x;
  int tot = E + n;
  if (i >= tot) return;
  if (i < E) {
    if (*flag) {
      const int* p = (const int*)raw;
      src[i] = p[i];
      dst[i] = p[E + i];
    } else {
      const long long* p = (const long long*)raw;
      src[i] = (int)p[i];
      dst[i] = (int)p[E + i];
    }
  } else {                 // self loops appended
    src[i] = i - E;
    dst[i] = i - E;
  }
}

// ---------------------------------------------------------------------------
// CSR build: count -> scan -> fill
// ---------------------------------------------------------------------------
__global__ void count_kernel(const int* __restrict__ dst, int* __restrict__ counts, int etot) {
  int i = blockIdx.x * TPB + threadIdx.x;
  if (i < etot) atomicAdd(&counts[dst[i]], 1);
}

__global__ void scan_kernel(const int* __restrict__ counts, int* __restrict__ row_ptr, int n) {
  __shared__ int part[TPB];
  int tid = threadIdx.x;
  int chunk = (n + TPB - 1) / TPB;
  int begin = tid * chunk;
  int end = begin + chunk; if (end > n) end = n;
  int s = 0;
  for (int i = begin; i < end && i < n; i++) s += counts[i];
  part[tid] = s;
  __syncthreads();
  for (int off = 1; off < TPB; off <<= 1) {
    int v = (tid >= off) ? part[tid - off] : 0;
    __syncthreads();
    part[tid] += v;
    __syncthreads();
  }
  int base = (tid == 0) ? 0 : part[tid - 1];
  for (int i = begin; i < end && i < n; i++) { row_ptr[i] = base; base += counts[i]; }
  if (tid == TPB - 1) row_ptr[n] = base;
}

__global__ void fill_kernel(const int* __restrict__ src, const int* __restrict__ dst,
                            const int* __restrict__ row_ptr, int* __restrict__ fill,
                            int* __restrict__ sorted_src, int etot) {
  int i = blockIdx.x * TPB + threadIdx.x;
  if (i >= etot) return;
  int d = dst[i];
  int pos = row_ptr[d] + atomicAdd(&fill[d], 1);
  sorted_src[pos] = src[i];
}

// ---------------------------------------------------------------------------
// fp32 -> bf16 convert (linear)
// ---------------------------------------------------------------------------
__global__ void f32_to_bf16_kernel(const float* __restrict__ in, __hip_bfloat16* __restrict__ out, int n) {
  int i = blockIdx.x * TPB + threadIdx.x;
  if (i < n) out[i] = __float2bfloat16(in[i]);
}

// fp32 [K][N] -> bf16 transposed [N][K]
__global__ void f32_to_bf16_T_kernel(const float* __restrict__ in, __hip_bfloat16* __restrict__ out,
                                     int K, int N) {
  __shared__ float tile[32][33];
  const int k0 = blockIdx.x * 32, n0 = blockIdx.y * 32;
  const int tx = threadIdx.x & 31, ty = threadIdx.x >> 5;   // 32 x 8
  for (int r = ty; r < 32; r += 8) {
    int k = k0 + r, n = n0 + tx;
    tile[r][tx] = (k < K && n < N) ? in[(size_t)k * N + n] : 0.f;
  }
  __syncthreads();
  for (int r = ty; r < 32; r += 8) {
    int n = n0 + r, k = k0 + tx;
    if (n < N && k < K) out[(size_t)n * K + k] = __float2bfloat16(tile[tx][r]);
  }
}

// ---------------------------------------------------------------------------
// bf16 MFMA GEMM with pre-transposed B: C[M,N] = A[M,K] @ Bt[N,K]^T (+bias).
// Tile 64(M) x 128(N), BK=32, 4 waves, mfma_f32_16x16x32_bf16.
// ---------------------------------------------------------------------------
__global__ __launch_bounds__(256) void gemm_bf16t_kernel(
    const short* __restrict__ A, const short* __restrict__ Bt,
    const float* __restrict__ bias, float* __restrict__ C,
    __hip_bfloat16* __restrict__ Cb, int M, int N, int K) {
  __shared__ short As[64][40];    // [row][k], 80B row stride
  __shared__ short Bs[128][40];   // [col][k]

  const int tid = threadIdx.x;
  const int lane = tid & 63;
  const int w = tid >> 6;
  const int bm = blockIdx.x * 64;
  const int bn = blockIdx.y * 128;

  f32x4 acc[8];
#pragma unroll
  for (int nt = 0; nt < 8; nt++) acc[nt] = (f32x4){0.f, 0.f, 0.f, 0.f};

  const int arow = tid >> 2;          // 0..63
  const int akk = (tid & 3) << 3;     // 0,8,16,24
  const int brow = tid >> 1;          // 0..127
  const int bkk = (tid & 1) << 4;     // 0,16

  for (int k0 = 0; k0 < K; k0 += 32) {
    {
      int gr = bm + arow;
      if (gr < M) {
        *(bf16x8*)&As[arow][akk] = *(const bf16x8*)&A[(size_t)gr * K + k0 + akk];
      } else {
        bf16x8 z = {0, 0, 0, 0, 0, 0, 0, 0};
        *(bf16x8*)&As[arow][akk] = z;
      }
    }
    {
      int gbn = bn + brow;
      if (gbn < N) {
        const short* bp = &Bt[(size_t)gbn * K + k0 + bkk];
        *(bf16x8*)&Bs[brow][bkk]     = *(const bf16x8*)bp;
        *(bf16x8*)&Bs[brow][bkk + 8] = *(const bf16x8*)(bp + 8);
      } else {
        bf16x8 z = {0, 0, 0, 0, 0, 0, 0, 0};
        *(bf16x8*)&Bs[brow][bkk] = z;
        *(bf16x8*)&Bs[brow][bkk + 8] = z;
      }
    }
    __syncthreads();

    bf16x8 a = *(const bf16x8*)&As[w * 16 + (lane & 15)][(lane >> 4) * 8];
#pragma unroll
    for (int nt = 0; nt < 8; nt++) {
      bf16x8 b = *(const bf16x8*)&Bs[nt * 16 + (lane & 15)][(lane >> 4) * 8];
      acc[nt] = __builtin_amdgcn_mfma_f32_16x16x32_bf16(a, b, acc[nt], 0, 0, 0);
    }
    __syncthreads();
  }

#pragma unroll
  for (int nt = 0; nt < 8; nt++) {
    int gc = bn + nt * 16 + (lane & 15);
    if (gc >= N) continue;
    float bv = bias ? bias[gc] : 0.f;
#pragma unroll
    for (int q = 0; q < 4; q++) {
      int gr = bm + w * 16 + (lane >> 4) * 4 + q;
      if (gr < M) {
        float val = acc[nt][q] + bv;
        if (C) C[(size_t)gr * N + gc] = val;
        if (Cb) Cb[(size_t)gr * N + gc] = __float2bfloat16(val);
      }
    }
  }
}

// ---------------------------------------------------------------------------
// attention coefficients, H=8 C=128, bf16 input g: block 256, one node/block
// ---------------------------------------------------------------------------
__global__ void attn_coeff8_kernel(const unsigned short* __restrict__ gb,
                                   const float* __restrict__ asrc,
                                   const float* __restrict__ adst,
                                   float* __restrict__ es, float* __restrict__ ed) {
  const int v = blockIdx.x;
  const int tid = threadIdx.x;
  ushort4 gu = *(const ushort4*)&gb[(size_t)v * 1024 + 4 * tid];
  float4 av = *(const float4*)&asrc[4 * tid];
  float4 dv = *(const float4*)&adst[4 * tid];
  float gx = bf2f(gu.x), gy = bf2f(gu.y), gz = bf2f(gu.z), gw = bf2f(gu.w);
  float p1 = gx * av.x + gy * av.y + gz * av.z + gw * av.w;
  float p2 = gx * dv.x + gy * dv.y + gz * dv.z + gw * dv.w;
#pragma unroll
  for (int off = 16; off > 0; off >>= 1) {
    p1 += __shfl_down(p1, off);
    p2 += __shfl_down(p2, off);
  }
  if ((tid & 31) == 0) {
    es[(size_t)v * 8 + (tid >> 5)] = p1;
    ed[(size_t)v * 8 + (tid >> 5)] = p2;
  }
}

// f32 variant for layer 2 (H=1, C=64)
template <int H, int C>
__global__ void attn_coeff_kernel(const float* __restrict__ g,
                                  const float* __restrict__ asrc,
                                  const float* __restrict__ adst,
                                  float* __restrict__ es, float* __restrict__ ed) {
  int v = blockIdx.x;
  int tid = threadIdx.x;
  __shared__ float rs[2], rd[2];
  const float* grow = g + (size_t)v * (H * C);
  for (int h = 0; h < H; ++h) {
    float gv = grow[h * C + tid];
    float p1 = gv * asrc[h * C + tid];
    float p2 = gv * adst[h * C + tid];
#pragma unroll
    for (int off = 32; off > 0; off >>= 1) {
      p1 += __shfl_down(p1, off);
      p2 += __shfl_down(p2, off);
    }
    if ((tid & 63) == 0) { rs[tid >> 6] = p1; rd[tid >> 6] = p2; }
    __syncthreads();
    if (tid == 0) {
      float s1 = rs[0], s2 = rd[0];
      if (C > 64) { s1 += rs[1]; s2 += rd[1]; }
      es[(size_t)v * H + h] = s1;
      ed[(size_t)v * H + h] = s2;
    }
    __syncthreads();
  }
}

// ---------------------------------------------------------------------------
// Per-dst softmax + aggregation, H=8 C=128, bf16 g.
// ONE WAVE PER NODE, no barriers, no LDS.
// Alpha phase lane map: ee = lane>>3 (edge in batch of 8), eh = lane&7 (head).
// Gather phase lane map: hh = lane>>3 (head), 16 channels/lane.
// Weights/srcs broadcast reg->reg via __shfl (ds_bpermute).
// ---------------------------------------------------------------------------
__global__ __launch_bounds__(256) void gat_aggregate8w_kernel(
    const int* __restrict__ row_ptr, const int* __restrict__ srcs,
    const unsigned short* __restrict__ gb, const float* __restrict__ es,
    const float* __restrict__ ed, const float* __restrict__ bias,
    float* __restrict__ out, int n) {
  const int wave = threadIdx.x >> 6;
  const int lane = threadIdx.x & 63;
  const int v = blockIdx.x * 4 + wave;
  if (v >= n) return;

  const int begin = row_ptr[v];
  const int deg = row_ptr[v + 1] - begin;

  const int eh = lane & 7;      // head (alpha phase)
  const int ee = lane >> 3;     // edge-in-batch (alpha phase)
  const int hh = lane >> 3;     // head (gather phase)
  const int c0 = lane << 4;     // 16 channels per lane in [0,1024)

  const float edv = ed[(size_t)v * 8 + eh];

  float acc[16];
#pragma unroll
  for (int k = 0; k < 16; k++) acc[k] = 0.f;

  if (deg <= 64) {
    // ---- alpha for all edges, register-resident ----
    float a[8];
    int sreg[8];
#pragma unroll
    for (int b = 0; b < 8; b++) {
      a[b] = -1e30f;
      sreg[b] = 0;
      int e = b * 8 + ee;
      if (e < deg) {
        int s = srcs[begin + e];
        sreg[b] = s;
        float t = es[(size_t)s * 8 + eh] + edv;
        a[b] = t > 0.f ? t : 0.2f * t;
      }
    }
    // per-head max: over regs, then lanes with stride 8/16/32
    float m = a[0];
#pragma unroll
    for (int b = 1; b < 8; b++) m = fmaxf(m, a[b]);
    m = fmaxf(m, __shfl_xor(m, 8));
    m = fmaxf(m, __shfl_xor(m, 16));
    m = fmaxf(m, __shfl_xor(m, 32));
    // exp + denom
    float dsum = 0.f;
#pragma unroll
    for (int b = 0; b < 8; b++) { a[b] = __expf(a[b] - m); dsum += a[b]; }
    dsum += __shfl_xor(dsum, 8);
    dsum += __shfl_xor(dsum, 16);
    dsum += __shfl_xor(dsum, 32);
    const float invd = 1.0f / (dsum + 1e-16f);
#pragma unroll
    for (int b = 0; b < 8; b++) a[b] *= invd;   // final weights

    // ---- gather: edge j -> srcLane ((j&7)<<3)|hh holds (s, w[hh]) ----
#pragma unroll
    for (int b = 0; b < 8; b++) {
      if (b * 8 >= deg) break;
#pragma unroll
      for (int jj = 0; jj < 8; jj++) {
        if (b * 8 + jj >= deg) break;
        const int sl = (jj << 3) | hh;
        const int s = __shfl(sreg[b], sl);
        const float w = __shfl(a[b], sl);
        const ushort8* p = (const ushort8*)&gb[(size_t)s * 1024 + c0];
        ushort8 u0 = p[0], u1 = p[1];
#pragma unroll
        for (int k = 0; k < 8; k++) {
          acc[k]     += w * bf2f(u0[k]);
          acc[k + 8] += w * bf2f(u1[k]);
        }
      }
    }
  } else {
    // ---- slow path (deg > 64): recompute sweeps, uniform branches ----
    float m = -1e30f;
    for (int base = 0; base < deg; base += 8) {
      int e = base + ee;
      if (e < deg) {
        int s = srcs[begin + e];
        float t = es[(size_t)s * 8 + eh] + edv;
        t = t > 0.f ? t : 0.2f * t;
        m = fmaxf(m, t);
      }
    }
    m = fmaxf(m, __shfl_xor(m, 8));
    m = fmaxf(m, __shfl_xor(m, 16));
    m = fmaxf(m, __shfl_xor(m, 32));
    float dsum = 0.f;
    for (int base = 0; base < deg; base += 8) {
      int e = base + ee;
      if (e < deg) {
        int s = srcs[begin + e];
        float t = es[(size_t)s * 8 + eh] + edv;
        t = t > 0.f ? t : 0.2f * t;
        dsum += __expf(t - m);
      }
    }
    dsum += __shfl_xor(dsum, 8);
    dsum += __shfl_xor(dsum, 16);
    dsum += __shfl_xor(dsum, 32);
    const float invd = 1.0f / (dsum + 1e-16f);
    for (int base = 0; base < deg; base += 8) {
      int e = base + ee;
      float w = 0.f; int s = 0;
      if (e < deg) {
        s = srcs[begin + e];
        float t = es[(size_t)s * 8 + eh] + edv;
        t = t > 0.f ? t : 0.2f * t;
        w = __expf(t - m) * invd;
      }
#pragma unroll
      for (int jj = 0; jj < 8; jj++) {
        if (base + jj >= deg) break;
        const int sl = (jj << 3) | hh;
        const int ss = __shfl(s, sl);
        const float ww = __shfl(w, sl);
        const ushort8* p = (const ushort8*)&gb[(size_t)ss * 1024 + c0];
        ushort8 u0 = p[0], u1 = p[1];
#pragma unroll
        for (int k = 0; k < 8; k++) {
          acc[k]     += ww * bf2f(u0[k]);
          acc[k + 8] += ww * bf2f(u1[k]);
        }
      }
    }
  }

  // ---- head-mean: sum across lanes with same (lane&7), write by hh==0 ----
#pragma unroll
  for (int k = 0; k < 16; k++) {
    acc[k] += __shfl_xor(acc[k], 8);
    acc[k] += __shfl_xor(acc[k], 16);
    acc[k] += __shfl_xor(acc[k], 32);
  }
  if (hh == 0) {
    const int cc = (lane & 7) << 4;   // 16-channel block in [0,128)
#pragma unroll
    for (int k = 0; k < 16; k++)
      out[(size_t)v * 128 + cc + k] = acc[k] * 0.125f + bias[cc + k];
  }
}

// ---------------------------------------------------------------------------
// Layer-2 aggregation (H=1, C=64): one WAVE per dst node, 4 nodes/block.
// ---------------------------------------------------------------------------
__global__ __launch_bounds__(256) void gat_aggregate1_kernel(
    const int* __restrict__ row_ptr, const int* __restrict__ srcs,
    const float* __restrict__ g, const float* __restrict__ es,
    const float* __restrict__ ed, const float* __restrict__ bias,
    float* __restrict__ out, int n) {
  const int wave = threadIdx.x >> 6;
  const int lane = threadIdx.x & 63;
  const int v = blockIdx.x * 4 + wave;
  if (v >= n) return;

  const int begin = row_ptr[v];
  const int deg = row_ptr[v + 1] - begin;
  const float edv = ed[v];

  float pm = -1e30f;
  for (int j = lane; j < deg; j += 64) {
    float a = es[srcs[begin + j]] + edv;
    a = a > 0.f ? a : 0.2f * a;
    pm = fmaxf(pm, a);
  }
#pragma unroll
  for (int off = 32; off > 0; off >>= 1) pm = fmaxf(pm, __shfl_xor(pm, off));

  float ps = 0.f;
  for (int j = lane; j < deg; j += 64) {
    float a = es[srcs[begin + j]] + edv;
    a = a > 0.f ? a : 0.2f * a;
    ps += expf(a - pm);
  }
#pragma unroll
  for (int off = 32; off > 0; off >>= 1) ps += __shfl_xor(ps, off);
  const float invd = 1.0f / (ps + 1e-16f);

  float acc = 0.f;
  for (int base = 0; base < deg; base += 64) {
    int cnt = deg - base; if (cnt > 64) cnt = 64;
    int sv = 0; float wv = 0.f;
    if (lane < cnt) {
      sv = srcs[begin + base + lane];
      float a = es[sv] + edv;
      a = a > 0.f ? a : 0.2f * a;
      wv = expf(a - pm) * invd;
    }
    for (int j = 0; j < cnt; j++) {
      int s = __shfl(sv, j);
      float wgt = __shfl(wv, j);
      acc += wgt * g[(size_t)s * 64 + lane];
    }
  }
  out[(size_t)v * 64 + lane] = acc + bias[lane];
}

// ---------------------------------------------------------------------------
// BN column stats
// ---------------------------------------------------------------------------
template <int C>
__global__ void bn_stats_kernel(const float* __restrict__ x, int n, float* __restrict__ sums) {
  constexpr int T = 256;
  constexpr int RPI = T / C;
  constexpr int ITER = 64;
  constexpr int ROWS = RPI * ITER;
  int c = threadIdx.x % C;
  int r0 = threadIdx.x / C;
  int rowBase = blockIdx.x * ROWS;
  float s = 0.f, q = 0.f;
  for (int it = 0; it < ITER; ++it) {
    int r = rowBase + it * RPI + r0;
    if (r < n) {
      float v = x[(size_t)r * C + c];
      s += v; q += v * v;
    }
  }
  __shared__ float ls[T], lq[T];
  ls[threadIdx.x] = s; lq[threadIdx.x] = q;
  __syncthreads();
  if (threadIdx.x < C) {
    float ts = 0.f, tq = 0.f;
    for (int r = 0; r < RPI; ++r) { ts += ls[c + r * C]; tq += lq[c + r * C]; }
    atomicAdd(&sums[c], ts);
    atomicAdd(&sums[C + c], tq);
  }
}

// ---------------------------------------------------------------------------
// out = elu(bn(x)) + res ; optional bf16 copy of out
// ---------------------------------------------------------------------------
template <int C>
__global__ void bn_elu_res_kernel(const float* __restrict__ x, const float* __restrict__ sums,
                                  const float* __restrict__ gamma, const float* __restrict__ beta,
                                  const float* __restrict__ res, float* __restrict__ out,
                                  __hip_bfloat16* __restrict__ outb, int n) {
  int i = blockIdx.x * TPB + threadIdx.x;
  if (i >= n * C) return;
  int c = i % C;
  float inv_n = 1.0f / (float)n;
  float mu = sums[c] * inv_n;
  float var = sums[C + c] * inv_n - mu * mu;
  float y = (x[i] - mu) * rsqrtf(var + 1e-5f) * gamma[c] + beta[c];
  y = y > 0.f ? y : expm1f(y);
  y += res[i];
  out[i] = y;
  if (outb) outb[i] = __float2bfloat16(y);
}

// ---------------------------------------------------------------------------
// host launch
// ---------------------------------------------------------------------------
extern "C" void kernel_launch(void* const* d_in, const int* in_sizes, int n_in,
                              void* d_out, int out_size, void* d_ws, size_t ws_size,
                              hipStream_t stream) {
  const float* x   = (const float*)d_in[0];
  const void*  ei  = d_in[1];
  const float* Wp  = (const float*)d_in[2];
  const float* bp  = (const float*)d_in[3];
  const float* W0  = (const float*)d_in[4];
  const float* as0 = (const float*)d_in[5];
  const float* ad0 = (const float*)d_in[6];
  const float* b0  = (const float*)d_in[7];
  const float* g0  = (const float*)d_in[8];
  const float* be0 = (const float*)d_in[9];
  const float* W1  = (const float*)d_in[10];
  const float* as1 = (const float*)d_in[11];
  const float* ad1 = (const float*)d_in[12];
  const float* b1  = (const float*)d_in[13];
  const float* g1  = (const float*)d_in[14];
  const float* be1 = (const float*)d_in[15];
  const float* W2  = (const float*)d_in[16];
  const float* as2 = (const float*)d_in[17];
  const float* ad2 = (const float*)d_in[18];
  const float* b2  = (const float*)d_in[19];
  const float* g2  = (const float*)d_in[20];
  const float* be2 = (const float*)d_in[21];
  const float* Wr  = (const float*)d_in[22];
  const float* br  = (const float*)d_in[23];

  const int N = in_sizes[0] / 64;       // 10000
  const int E = in_sizes[1] / 2;        // 160000
  const int ETOT = E + N;

  char* wsp = (char*)d_ws;
  size_t off = 0;
  auto alloc = [&](size_t bytes) -> void* {
    void* p = wsp + off;
    off += (bytes + 255) & ~(size_t)255;
    return p;
  };
  int*   flag    = (int*)alloc(4);
  int*   e_src   = (int*)alloc((size_t)ETOT * 4);
  int*   e_dst   = (int*)alloc((size_t)ETOT * 4);
  int*   counts  = (int*)alloc((size_t)N * 4);
  int*   fillc   = (int*)alloc((size_t)N * 4);
  int*   row_ptr = (int*)alloc((size_t)(N + 1) * 4);
  int*   s_src   = (int*)alloc((size_t)ETOT * 4);
  float* hA      = (float*)alloc((size_t)N * 128 * 4);
  float* hB      = (float*)alloc((size_t)N * 128 * 4);
  float* gbuf    = (float*)alloc((size_t)N * 64 * 4);       // layer-2 g (f32)
  float* gat     = (float*)alloc((size_t)N * 128 * 4);
  float* es      = (float*)alloc((size_t)N * 8 * 4);
  float* ed      = (float*)alloc((size_t)N * 8 * 4);
  float* bnsum   = (float*)alloc(2 * 128 * 4);
  __hip_bfloat16* gbufb = (__hip_bfloat16*)alloc((size_t)N * 1024 * 2);  // big-layer g (bf16)
  __hip_bfloat16* xb  = (__hip_bfloat16*)alloc((size_t)N * 64 * 2);
  __hip_bfloat16* hAb = (__hip_bfloat16*)alloc((size_t)N * 128 * 2);
  __hip_bfloat16* hBb = (__hip_bfloat16*)alloc((size_t)N * 128 * 2);
  __hip_bfloat16* WpT = (__hip_bfloat16*)alloc((size_t)128 * 64 * 2);   // [128][64]
  __hip_bfloat16* W0T = (__hip_bfloat16*)alloc((size_t)1024 * 128 * 2); // [1024][128]
  __hip_bfloat16* W1T = (__hip_bfloat16*)alloc((size_t)1024 * 128 * 2);
  __hip_bfloat16* W2T = (__hip_bfloat16*)alloc((size_t)64 * 128 * 2);
  __hip_bfloat16* WrT = (__hip_bfloat16*)alloc((size_t)64 * 128 * 2);

  const int egrid = (ETOT + TPB - 1) / TPB;
  const int mgrid = (N + 63) / 64;      // 157
  auto cgrid = [](int n) { return (n + TPB - 1) / TPB; };

  // ---- graph prep ----
  detect_kernel<<<1, TPB, 0, stream>>>((const unsigned int*)ei, flag);
  decode_kernel<<<egrid, TPB, 0, stream>>>(ei, flag, e_src, e_dst, E, N);
  hipMemsetAsync(counts, 0, (size_t)N * 4, stream);
  hipMemsetAsync(fillc, 0, (size_t)N * 4, stream);
  count_kernel<<<egrid, TPB, 0, stream>>>(e_dst, counts, ETOT);
  scan_kernel<<<1, TPB, 0, stream>>>(counts, row_ptr, N);
  fill_kernel<<<egrid, TPB, 0, stream>>>(e_src, e_dst, row_ptr, fillc, s_src, ETOT);

  // ---- weight / input conversions (weights transposed for GEMM B) ----
  f32_to_bf16_kernel<<<cgrid(N * 64), TPB, 0, stream>>>(x, xb, N * 64);
  f32_to_bf16_T_kernel<<<dim3(2, 4), 256, 0, stream>>>(Wp, WpT, 64, 128);
  f32_to_bf16_T_kernel<<<dim3(4, 32), 256, 0, stream>>>(W0, W0T, 128, 1024);
  f32_to_bf16_T_kernel<<<dim3(4, 32), 256, 0, stream>>>(W1, W1T, 128, 1024);
  f32_to_bf16_T_kernel<<<dim3(4, 2), 256, 0, stream>>>(W2, W2T, 128, 64);
  f32_to_bf16_T_kernel<<<dim3(4, 2), 256, 0, stream>>>(Wr, WrT, 128, 64);

  // ---- projection: hA = x @ Wp + bp (also bf16 copy hAb) ----
  gemm_bf16t_kernel<<<dim3(mgrid, 1), 256, 0, stream>>>(
      (const short*)xb, (const short*)WpT, bp, hA, hAb, N, 128, 64);

  // ---- layer 0 (g written bf16-only) ----
  gemm_bf16t_kernel<<<dim3(mgrid, 8), 256, 0, stream>>>(
      (const short*)hAb, (const short*)W0T, nullptr, nullptr, gbufb, N, 1024, 128);
  attn_coeff8_kernel<<<N, 256, 0, stream>>>((const unsigned short*)gbufb, as0, ad0, es, ed);
  gat_aggregate8w_kernel<<<(N + 3) / 4, 256, 0, stream>>>(
      row_ptr, s_src, (const unsigned short*)gbufb, es, ed, b0, gat, N);
  hipMemsetAsync(bnsum, 0, 2 * 128 * 4, stream);
  bn_stats_kernel<128><<<(N + 127) / 128, 256, 0, stream>>>(gat, N, bnsum);
  bn_elu_res_kernel<128><<<cgrid(N * 128), TPB, 0, stream>>>(gat, bnsum, g0, be0, hA, hB, hBb, N);

  // ---- layer 1 ----
  gemm_bf16t_kernel<<<dim3(mgrid, 8), 256, 0, stream>>>(
      (const short*)hBb, (const short*)W1T, nullptr, nullptr, gbufb, N, 1024, 128);
  attn_coeff8_kernel<<<N, 256, 0, stream>>>((const unsigned short*)gbufb, as1, ad1, es, ed);
  gat_aggregate8w_kernel<<<(N + 3) / 4, 256, 0, stream>>>(
      row_ptr, s_src, (const unsigned short*)gbufb, es, ed, b1, gat, N);
  hipMemsetAsync(bnsum, 0, 2 * 128 * 4, stream);
  bn_stats_kernel<128><<<(N + 127) / 128, 256, 0, stream>>>(gat, N, bnsum);
  bn_elu_res_kernel<128><<<cgrid(N * 128), TPB, 0, stream>>>(gat, bnsum, g1, be1, hB, hA, hAb, N);

  // ---- layer 2 (H=1, C=64) ----
  gemm_bf16t_kernel<<<dim3(mgrid, 1), 256, 0, stream>>>(
      (const short*)hAb, (const short*)WrT, br, hB, nullptr, N, 64, 128);    // hr
  gemm_bf16t_kernel<<<dim3(mgrid, 1), 256, 0, stream>>>(
      (const short*)hAb, (const short*)W2T, nullptr, gbuf, nullptr, N, 64, 128);
  attn_coeff_kernel<1, 64><<<N, 64, 0, stream>>>(gbuf, as2, ad2, es, ed);
  gat_aggregate1_kernel<<<(N + 3) / 4, 256, 0, stream>>>(row_ptr, s_src, gbuf, es, ed, b2, gat, N);
  hipMemsetAsync(bnsum, 0, 2 * 64 * 4, stream);
  bn_stats_kernel<64><<<(N + 255) / 256, 256, 0, stream>>>(gat, N, bnsum);
  bn_elu_res_kernel<64><<<cgrid(N * 64), TPB, 0, stream>>>(gat, bnsum, g2, be2, hB, (float*)d_out, nullptr, N);
}

// Round 6
// 321.223 us; speedup vs baseline: 1.0612x; 1.0461x over previous
//
#include <hip/hip_runtime.h>
#include <hip/hip_bf16.h>
#include <cstdint>
#include <cstddef>

#define TPB 256

typedef __attribute__((ext_vector_type(8))) short bf16x8;
typedef __attribute__((ext_vector_type(8))) unsigned short ushort8;
typedef __attribute__((ext_vector_type(4))) float f32x4;

static __device__ __forceinline__ float bf2f(unsigned short u) {
  union { unsigned int i; float f; } c;
  c.i = ((unsigned int)u) << 16;
  return c.f;
}

// ---------------------------------------------------------------------------
// Edge dtype detection
// ---------------------------------------------------------------------------
__global__ void detect_kernel(const unsigned int* __restrict__ w, int* __restrict__ flag) {
  __shared__ int any32;
  if (threadIdx.x == 0) any32 = 0;
  __syncthreads();
  for (int i = threadIdx.x; i < 1024; i += TPB)
    if (w[2 * i + 1] != 0u) any32 = 1;
  __syncthreads();
  if (threadIdx.x == 0) *flag = any32;   // 1 -> int32 data, 0 -> int64 data
}

__global__ void decode_kernel(const void* __restrict__ raw, const int* __restrict__ flag,
                              int* __restrict__ src, int* __restrict__ dst, int E, int n) {
  int i = blockIdx.x * TPB + threadIdx.x;
  int tot = E + n;
  if (i >= tot) return;
  if (i < E) {
    if (*flag) {
      const int* p = (const int*)raw;
      src[i] = p[i];
      dst[i] = p[E + i];
    } else {
      const long long* p = (const long long*)raw;
      src[i] = (int)p[i];
      dst[i] = (int)p[E + i];
    }
  } else {
    src[i] = i - E;
    dst[i] = i - E;
  }
}

// ---------------------------------------------------------------------------
// CSR build: count -> scan -> fill
// ---------------------------------------------------------------------------
__global__ void count_kernel(const int* __restrict__ dst, int* __restrict__ counts, int etot) {
  int i = blockIdx.x * TPB + threadIdx.x;
  if (i < etot) atomicAdd(&counts[dst[i]], 1);
}

__global__ void scan_kernel(const int* __restrict__ counts, int* __restrict__ row_ptr, int n) {
  __shared__ int part[TPB];
  int tid = threadIdx.x;
  int chunk = (n + TPB - 1) / TPB;
  int begin = tid * chunk;
  int end = begin + chunk; if (end > n) end = n;
  int s = 0;
  for (int i = begin; i < end && i < n; i++) s += counts[i];
  part[tid] = s;
  __syncthreads();
  for (int off = 1; off < TPB; off <<= 1) {
    int v = (tid >= off) ? part[tid - off] : 0;
    __syncthreads();
    part[tid] += v;
    __syncthreads();
  }
  int base = (tid == 0) ? 0 : part[tid - 1];
  for (int i = begin; i < end && i < n; i++) { row_ptr[i] = base; base += counts[i]; }
  if (tid == TPB - 1) row_ptr[n] = base;
}

__global__ void fill_kernel(const int* __restrict__ src, const int* __restrict__ dst,
                            const int* __restrict__ row_ptr, int* __restrict__ fill,
                            int* __restrict__ sorted_src, int etot) {
  int i = blockIdx.x * TPB + threadIdx.x;
  if (i >= etot) return;
  int d = dst[i];
  int pos = row_ptr[d] + atomicAdd(&fill[d], 1);
  sorted_src[pos] = src[i];
}

// ---------------------------------------------------------------------------
// fp32 -> bf16 convert (linear)
// ---------------------------------------------------------------------------
__global__ void f32_to_bf16_kernel(const float* __restrict__ in, __hip_bfloat16* __restrict__ out, int n) {
  int i = blockIdx.x * TPB + threadIdx.x;
  if (i < n) out[i] = __float2bfloat16(in[i]);
}

// fp32 [K][N] -> bf16 transposed [N][K]
__global__ void f32_to_bf16_T_kernel(const float* __restrict__ in, __hip_bfloat16* __restrict__ out,
                                     int K, int N) {
  __shared__ float tile[32][33];
  const int k0 = blockIdx.x * 32, n0 = blockIdx.y * 32;
  const int tx = threadIdx.x & 31, ty = threadIdx.x >> 5;   // 32 x 8
  for (int r = ty; r < 32; r += 8) {
    int k = k0 + r, n = n0 + tx;
    tile[r][tx] = (k < K && n < N) ? in[(size_t)k * N + n] : 0.f;
  }
  __syncthreads();
  for (int r = ty; r < 32; r += 8) {
    int n = n0 + r, k = k0 + tx;
    if (n < N && k < K) out[(size_t)n * K + k] = __float2bfloat16(tile[tx][r]);
  }
}

// ---------------------------------------------------------------------------
// bf16 MFMA GEMM with pre-transposed B: C[M,N] = A[M,K] @ Bt[N,K]^T (+bias).
// Tile 64(M) x 128(N), BK=32, 4 waves, mfma_f32_16x16x32_bf16.
// Optional fused attention coefficients: es[r,head] = sum_c val*asrc[gc],
// ed likewise. Requires each 128-col block to lie within ONE head
// (head = bn >> hshift); asrc/adst flat index == output column gc.
// ---------------------------------------------------------------------------
__global__ __launch_bounds__(256) void gemm_bf16t_kernel(
    const short* __restrict__ A, const short* __restrict__ Bt,
    const float* __restrict__ bias, float* __restrict__ C,
    __hip_bfloat16* __restrict__ Cb, int M, int Ncols, int K,
    const float* __restrict__ asrc, const float* __restrict__ adst,
    float* __restrict__ es_out, float* __restrict__ ed_out, int H, int hshift) {
  __shared__ short As[64][40];    // [row][k], 80B row stride
  __shared__ short Bs[128][40];   // [col][k]

  const int tid = threadIdx.x;
  const int lane = tid & 63;
  const int w = tid >> 6;
  const int bm = blockIdx.x * 64;
  const int bn = blockIdx.y * 128;

  f32x4 acc[8];
#pragma unroll
  for (int nt = 0; nt < 8; nt++) acc[nt] = (f32x4){0.f, 0.f, 0.f, 0.f};

  const int arow = tid >> 2;          // 0..63
  const int akk = (tid & 3) << 3;     // 0,8,16,24
  const int brow = tid >> 1;          // 0..127
  const int bkk = (tid & 1) << 4;     // 0,16

  for (int k0 = 0; k0 < K; k0 += 32) {
    {
      int gr = bm + arow;
      if (gr < M) {
        *(bf16x8*)&As[arow][akk] = *(const bf16x8*)&A[(size_t)gr * K + k0 + akk];
      } else {
        bf16x8 z = {0, 0, 0, 0, 0, 0, 0, 0};
        *(bf16x8*)&As[arow][akk] = z;
      }
    }
    {
      int gbn = bn + brow;
      if (gbn < Ncols) {
        const short* bp = &Bt[(size_t)gbn * K + k0 + bkk];
        *(bf16x8*)&Bs[brow][bkk]     = *(const bf16x8*)bp;
        *(bf16x8*)&Bs[brow][bkk + 8] = *(const bf16x8*)(bp + 8);
      } else {
        bf16x8 z = {0, 0, 0, 0, 0, 0, 0, 0};
        *(bf16x8*)&Bs[brow][bkk] = z;
        *(bf16x8*)&Bs[brow][bkk + 8] = z;
      }
    }
    __syncthreads();

    bf16x8 a = *(const bf16x8*)&As[w * 16 + (lane & 15)][(lane >> 4) * 8];
#pragma unroll
    for (int nt = 0; nt < 8; nt++) {
      bf16x8 b = *(const bf16x8*)&Bs[nt * 16 + (lane & 15)][(lane >> 4) * 8];
      acc[nt] = __builtin_amdgcn_mfma_f32_16x16x32_bf16(a, b, acc[nt], 0, 0, 0);
    }
    __syncthreads();
  }

  float p1[4] = {0.f, 0.f, 0.f, 0.f};
  float p2[4] = {0.f, 0.f, 0.f, 0.f};

#pragma unroll
  for (int nt = 0; nt < 8; nt++) {
    int gc = bn + nt * 16 + (lane & 15);
    if (gc >= Ncols) continue;
    float bv = bias ? bias[gc] : 0.f;
    float asv = es_out ? asrc[gc] : 0.f;
    float adv = es_out ? adst[gc] : 0.f;
#pragma unroll
    for (int q = 0; q < 4; q++) {
      int gr = bm + w * 16 + (lane >> 4) * 4 + q;
      if (gr < M) {
        float val = acc[nt][q] + bv;
        if (C) C[(size_t)gr * Ncols + gc] = val;
        if (Cb) Cb[(size_t)gr * Ncols + gc] = __float2bfloat16(val);
        p1[q] += val * asv;
        p2[q] += val * adv;
      }
    }
  }

  if (es_out) {
    const int head = bn >> hshift;
#pragma unroll
    for (int q = 0; q < 4; q++) {
      float s1 = p1[q], s2 = p2[q];
      s1 += __shfl_xor(s1, 1); s2 += __shfl_xor(s2, 1);
      s1 += __shfl_xor(s1, 2); s2 += __shfl_xor(s2, 2);
      s1 += __shfl_xor(s1, 4); s2 += __shfl_xor(s2, 4);
      s1 += __shfl_xor(s1, 8); s2 += __shfl_xor(s2, 8);
      int gr = bm + w * 16 + (lane >> 4) * 4 + q;
      if ((lane & 15) == 0 && gr < M) {
        es_out[(size_t)gr * H + head] = s1;
        ed_out[(size_t)gr * H + head] = s2;
      }
    }
  }
}

// ---------------------------------------------------------------------------
// Per-dst softmax + aggregation, H=8 C=128, bf16 g.
// One wave per node. Alpha phase in registers (lane = edge-octet x head),
// weights/srcs spilled to per-wave LDS padded with w=0 to 64 edges, then a
// BRANCH-FREE gather loop: 4 edges/iter -> 8 independent 16B loads in flight.
// ---------------------------------------------------------------------------
__global__ __launch_bounds__(256) void gat_aggregate8w_kernel(
    const int* __restrict__ row_ptr, const int* __restrict__ srcs,
    const unsigned short* __restrict__ gb, const float* __restrict__ es,
    const float* __restrict__ ed, const float* __restrict__ bias,
    float* __restrict__ out, int n) {
  const int wave = threadIdx.x >> 6;
  const int lane = threadIdx.x & 63;
  const int v = blockIdx.x * 4 + wave;

  __shared__ float wlds[4][64][8];
  __shared__ int slds[4][64];

  if (v >= n) return;

  const int begin = row_ptr[v];
  const int deg = row_ptr[v + 1] - begin;

  const int eh = lane & 7;      // head (alpha phase)
  const int ee = lane >> 3;     // edge-in-octet (alpha phase)
  const int hh = lane >> 3;     // head (gather phase)
  const int c0 = lane << 4;     // 16 channels per lane in [0,1024)

  const float edv = ed[(size_t)v * 8 + eh];

  float acc[16];
#pragma unroll
  for (int k = 0; k < 16; k++) acc[k] = 0.f;

  if (deg <= 64) {
    // ---- alpha for all edges, register-resident ----
    float a[8];
    int sreg[8];
#pragma unroll
    for (int b = 0; b < 8; b++) {
      a[b] = -1e30f;
      sreg[b] = 0;
      int e = b * 8 + ee;
      if (e < deg) {
        int s = srcs[begin + e];
        sreg[b] = s;
        float t = es[(size_t)s * 8 + eh] + edv;
        a[b] = t > 0.f ? t : 0.2f * t;
      }
    }
    float m = a[0];
#pragma unroll
    for (int b = 1; b < 8; b++) m = fmaxf(m, a[b]);
    m = fmaxf(m, __shfl_xor(m, 8));
    m = fmaxf(m, __shfl_xor(m, 16));
    m = fmaxf(m, __shfl_xor(m, 32));
    float dsum = 0.f;
#pragma unroll
    for (int b = 0; b < 8; b++) { a[b] = __expf(a[b] - m); dsum += a[b]; }
    dsum += __shfl_xor(dsum, 8);
    dsum += __shfl_xor(dsum, 16);
    dsum += __shfl_xor(dsum, 32);
    const float invd = 1.0f / (dsum + 1e-16f);
    // spill weights (0 beyond deg) + srcs to LDS; addr = b*64+lane (no conflict)
#pragma unroll
    for (int b = 0; b < 8; b++) {
      wlds[wave][b * 8 + ee][eh] = a[b] * invd;
      if (eh == 0) slds[wave][b * 8 + ee] = sreg[b];
    }

    // ---- branch-free gather, 4 edges/iter ----
    const int npad = (deg + 3) & ~3;
    for (int j0 = 0; j0 < npad; j0 += 4) {
      float w0 = wlds[wave][j0 + 0][hh];
      float w1 = wlds[wave][j0 + 1][hh];
      float w2 = wlds[wave][j0 + 2][hh];
      float w3 = wlds[wave][j0 + 3][hh];
      int s0 = slds[wave][j0 + 0];
      int s1 = slds[wave][j0 + 1];
      int s2 = slds[wave][j0 + 2];
      int s3 = slds[wave][j0 + 3];
      const ushort8* p0 = (const ushort8*)&gb[(size_t)s0 * 1024 + c0];
      const ushort8* p1 = (const ushort8*)&gb[(size_t)s1 * 1024 + c0];
      const ushort8* p2 = (const ushort8*)&gb[(size_t)s2 * 1024 + c0];
      const ushort8* p3 = (const ushort8*)&gb[(size_t)s3 * 1024 + c0];
      ushort8 u0a = p0[0], u0b = p0[1];
      ushort8 u1a = p1[0], u1b = p1[1];
      ushort8 u2a = p2[0], u2b = p2[1];
      ushort8 u3a = p3[0], u3b = p3[1];
#pragma unroll
      for (int k = 0; k < 8; k++) {
        acc[k]     += w0 * bf2f(u0a[k]) + w1 * bf2f(u1a[k]) + w2 * bf2f(u2a[k]) + w3 * bf2f(u3a[k]);
        acc[k + 8] += w0 * bf2f(u0b[k]) + w1 * bf2f(u1b[k]) + w2 * bf2f(u2b[k]) + w3 * bf2f(u3b[k]);
      }
    }
  } else {
    // ---- slow path (deg > 64): sweeps for m/denom, then 64-edge chunks ----
    float m = -1e30f;
    for (int base = ee; base < deg; base += 8) {
      int s = srcs[begin + base];
      float t = es[(size_t)s * 8 + eh] + edv;
      t = t > 0.f ? t : 0.2f * t;
      m = fmaxf(m, t);
    }
    m = fmaxf(m, __shfl_xor(m, 8));
    m = fmaxf(m, __shfl_xor(m, 16));
    m = fmaxf(m, __shfl_xor(m, 32));
    float dsum = 0.f;
    for (int base = ee; base < deg; base += 8) {
      int s = srcs[begin + base];
      float t = es[(size_t)s * 8 + eh] + edv;
      t = t > 0.f ? t : 0.2f * t;
      dsum += __expf(t - m);
    }
    dsum += __shfl_xor(dsum, 8);
    dsum += __shfl_xor(dsum, 16);
    dsum += __shfl_xor(dsum, 32);
    const float invd = 1.0f / (dsum + 1e-16f);

    for (int base = 0; base < deg; base += 64) {
      const int cnt = min(64, deg - base);
#pragma unroll
      for (int b = 0; b < 8; b++) {
        int e = base + b * 8 + ee;
        float wv = 0.f;
        int s = 0;
        if (e < deg) {
          s = srcs[begin + e];
          float t = es[(size_t)s * 8 + eh] + edv;
          t = t > 0.f ? t : 0.2f * t;
          wv = __expf(t - m) * invd;
        }
        wlds[wave][b * 8 + ee][eh] = wv;
        if (eh == 0) slds[wave][b * 8 + ee] = s;
      }
      const int npad = (cnt + 3) & ~3;
      for (int j0 = 0; j0 < npad; j0 += 4) {
        float w0 = wlds[wave][j0 + 0][hh];
        float w1 = wlds[wave][j0 + 1][hh];
        float w2 = wlds[wave][j0 + 2][hh];
        float w3 = wlds[wave][j0 + 3][hh];
        int s0 = slds[wave][j0 + 0];
        int s1 = slds[wave][j0 + 1];
        int s2 = slds[wave][j0 + 2];
        int s3 = slds[wave][j0 + 3];
        const ushort8* p0 = (const ushort8*)&gb[(size_t)s0 * 1024 + c0];
        const ushort8* p1 = (const ushort8*)&gb[(size_t)s1 * 1024 + c0];
        const ushort8* p2 = (const ushort8*)&gb[(size_t)s2 * 1024 + c0];
        const ushort8* p3 = (const ushort8*)&gb[(size_t)s3 * 1024 + c0];
        ushort8 u0a = p0[0], u0b = p0[1];
        ushort8 u1a = p1[0], u1b = p1[1];
        ushort8 u2a = p2[0], u2b = p2[1];
        ushort8 u3a = p3[0], u3b = p3[1];
#pragma unroll
        for (int k = 0; k < 8; k++) {
          acc[k]     += w0 * bf2f(u0a[k]) + w1 * bf2f(u1a[k]) + w2 * bf2f(u2a[k]) + w3 * bf2f(u3a[k]);
          acc[k + 8] += w0 * bf2f(u0b[k]) + w1 * bf2f(u1b[k]) + w2 * bf2f(u2b[k]) + w3 * bf2f(u3b[k]);
        }
      }
    }
  }

  // ---- head-mean across lanes with same (lane&7), write by hh==0 ----
#pragma unroll
  for (int k = 0; k < 16; k++) {
    acc[k] += __shfl_xor(acc[k], 8);
    acc[k] += __shfl_xor(acc[k], 16);
    acc[k] += __shfl_xor(acc[k], 32);
  }
  if (hh == 0) {
    const int cc = (lane & 7) << 4;
#pragma unroll
    for (int k = 0; k < 16; k++)
      out[(size_t)v * 128 + cc + k] = acc[k] * 0.125f + bias[cc + k];
  }
}

// ---------------------------------------------------------------------------
// Layer-2 aggregation (H=1, C=64): one WAVE per dst node, 4 nodes/block.
// ---------------------------------------------------------------------------
__global__ __launch_bounds__(256) void gat_aggregate1_kernel(
    const int* __restrict__ row_ptr, const int* __restrict__ srcs,
    const float* __restrict__ g, const float* __restrict__ es,
    const float* __restrict__ ed, const float* __restrict__ bias,
    float* __restrict__ out, int n) {
  const int wave = threadIdx.x >> 6;
  const int lane = threadIdx.x & 63;
  const int v = blockIdx.x * 4 + wave;
  if (v >= n) return;

  const int begin = row_ptr[v];
  const int deg = row_ptr[v + 1] - begin;
  const float edv = ed[v];

  float pm = -1e30f;
  for (int j = lane; j < deg; j += 64) {
    float a = es[srcs[begin + j]] + edv;
    a = a > 0.f ? a : 0.2f * a;
    pm = fmaxf(pm, a);
  }
#pragma unroll
  for (int off = 32; off > 0; off >>= 1) pm = fmaxf(pm, __shfl_xor(pm, off));

  float ps = 0.f;
  for (int j = lane; j < deg; j += 64) {
    float a = es[srcs[begin + j]] + edv;
    a = a > 0.f ? a : 0.2f * a;
    ps += expf(a - pm);
  }
#pragma unroll
  for (int off = 32; off > 0; off >>= 1) ps += __shfl_xor(ps, off);
  const float invd = 1.0f / (ps + 1e-16f);

  float acc = 0.f;
  for (int base = 0; base < deg; base += 64) {
    int cnt = deg - base; if (cnt > 64) cnt = 64;
    int sv = 0; float wv = 0.f;
    if (lane < cnt) {
      sv = srcs[begin + base + lane];
      float a = es[sv] + edv;
      a = a > 0.f ? a : 0.2f * a;
      wv = expf(a - pm) * invd;
    }
    for (int j = 0; j < cnt; j++) {
      int s = __shfl(sv, j);
      float wgt = __shfl(wv, j);
      acc += wgt * g[(size_t)s * 64 + lane];
    }
  }
  out[(size_t)v * 64 + lane] = acc + bias[lane];
}

// ---------------------------------------------------------------------------
// BN column stats
// ---------------------------------------------------------------------------
template <int C>
__global__ void bn_stats_kernel(const float* __restrict__ x, int n, float* __restrict__ sums) {
  constexpr int T = 256;
  constexpr int RPI = T / C;
  constexpr int ITER = 64;
  constexpr int ROWS = RPI * ITER;
  int c = threadIdx.x % C;
  int r0 = threadIdx.x / C;
  int rowBase = blockIdx.x * ROWS;
  float s = 0.f, q = 0.f;
  for (int it = 0; it < ITER; ++it) {
    int r = rowBase + it * RPI + r0;
    if (r < n) {
      float v = x[(size_t)r * C + c];
      s += v; q += v * v;
    }
  }
  __shared__ float ls[T], lq[T];
  ls[threadIdx.x] = s; lq[threadIdx.x] = q;
  __syncthreads();
  if (threadIdx.x < C) {
    float ts = 0.f, tq = 0.f;
    for (int r = 0; r < RPI; ++r) { ts += ls[c + r * C]; tq += lq[c + r * C]; }
    atomicAdd(&sums[c], ts);
    atomicAdd(&sums[C + c], tq);
  }
}

// ---------------------------------------------------------------------------
// out = elu(bn(x)) + res ; optional bf16 copy of out
// ---------------------------------------------------------------------------
template <int C>
__global__ void bn_elu_res_kernel(const float* __restrict__ x, const float* __restrict__ sums,
                                  const float* __restrict__ gamma, const float* __restrict__ beta,
                                  const float* __restrict__ res, float* __restrict__ out,
                                  __hip_bfloat16* __restrict__ outb, int n) {
  int i = blockIdx.x * TPB + threadIdx.x;
  if (i >= n * C) return;
  int c = i % C;
  float inv_n = 1.0f / (float)n;
  float mu = sums[c] * inv_n;
  float var = sums[C + c] * inv_n - mu * mu;
  float y = (x[i] - mu) * rsqrtf(var + 1e-5f) * gamma[c] + beta[c];
  y = y > 0.f ? y : expm1f(y);
  y += res[i];
  out[i] = y;
  if (outb) outb[i] = __float2bfloat16(y);
}

// ---------------------------------------------------------------------------
// host launch
// ---------------------------------------------------------------------------
extern "C" void kernel_launch(void* const* d_in, const int* in_sizes, int n_in,
                              void* d_out, int out_size, void* d_ws, size_t ws_size,
                              hipStream_t stream) {
  const float* x   = (const float*)d_in[0];
  const void*  ei  = d_in[1];
  const float* Wp  = (const float*)d_in[2];
  const float* bp  = (const float*)d_in[3];
  const float* W0  = (const float*)d_in[4];
  const float* as0 = (const float*)d_in[5];
  const float* ad0 = (const float*)d_in[6];
  const float* b0  = (const float*)d_in[7];
  const float* g0  = (const float*)d_in[8];
  const float* be0 = (const float*)d_in[9];
  const float* W1  = (const float*)d_in[10];
  const float* as1 = (const float*)d_in[11];
  const float* ad1 = (const float*)d_in[12];
  const float* b1  = (const float*)d_in[13];
  const float* g1  = (const float*)d_in[14];
  const float* be1 = (const float*)d_in[15];
  const float* W2  = (const float*)d_in[16];
  const float* as2 = (const float*)d_in[17];
  const float* ad2 = (const float*)d_in[18];
  const float* b2  = (const float*)d_in[19];
  const float* g2  = (const float*)d_in[20];
  const float* be2 = (const float*)d_in[21];
  const float* Wr  = (const float*)d_in[22];
  const float* br  = (const float*)d_in[23];

  const int N = in_sizes[0] / 64;       // 10000
  const int E = in_sizes[1] / 2;        // 160000
  const int ETOT = E + N;

  char* wsp = (char*)d_ws;
  size_t off = 0;
  auto alloc = [&](size_t bytes) -> void* {
    void* p = wsp + off;
    off += (bytes + 255) & ~(size_t)255;
    return p;
  };
  int*   flag    = (int*)alloc(4);
  int*   e_src   = (int*)alloc((size_t)ETOT * 4);
  int*   e_dst   = (int*)alloc((size_t)ETOT * 4);
  int*   counts  = (int*)alloc((size_t)N * 4);
  int*   fillc   = (int*)alloc((size_t)N * 4);
  int*   row_ptr = (int*)alloc((size_t)(N + 1) * 4);
  int*   s_src   = (int*)alloc((size_t)ETOT * 4);
  float* hA      = (float*)alloc((size_t)N * 128 * 4);
  float* hB      = (float*)alloc((size_t)N * 128 * 4);
  float* gbuf    = (float*)alloc((size_t)N * 64 * 4);       // layer-2 g (f32)
  float* gat     = (float*)alloc((size_t)N * 128 * 4);
  float* es      = (float*)alloc((size_t)N * 8 * 4);
  float* ed      = (float*)alloc((size_t)N * 8 * 4);
  float* bnsum   = (float*)alloc(2 * 128 * 4);
  __hip_bfloat16* gbufb = (__hip_bfloat16*)alloc((size_t)N * 1024 * 2);  // big-layer g (bf16)
  __hip_bfloat16* xb  = (__hip_bfloat16*)alloc((size_t)N * 64 * 2);
  __hip_bfloat16* hAb = (__hip_bfloat16*)alloc((size_t)N * 128 * 2);
  __hip_bfloat16* hBb = (__hip_bfloat16*)alloc((size_t)N * 128 * 2);
  __hip_bfloat16* WpT = (__hip_bfloat16*)alloc((size_t)128 * 64 * 2);   // [128][64]
  __hip_bfloat16* W0T = (__hip_bfloat16*)alloc((size_t)1024 * 128 * 2); // [1024][128]
  __hip_bfloat16* W1T = (__hip_bfloat16*)alloc((size_t)1024 * 128 * 2);
  __hip_bfloat16* W2T = (__hip_bfloat16*)alloc((size_t)64 * 128 * 2);
  __hip_bfloat16* WrT = (__hip_bfloat16*)alloc((size_t)64 * 128 * 2);

  const int egrid = (ETOT + TPB - 1) / TPB;
  const int mgrid = (N + 63) / 64;      // 157
  auto cgrid = [](int n) { return (n + TPB - 1) / TPB; };

  // ---- graph prep ----
  detect_kernel<<<1, TPB, 0, stream>>>((const unsigned int*)ei, flag);
  decode_kernel<<<egrid, TPB, 0, stream>>>(ei, flag, e_src, e_dst, E, N);
  hipMemsetAsync(counts, 0, (size_t)N * 4, stream);
  hipMemsetAsync(fillc, 0, (size_t)N * 4, stream);
  count_kernel<<<egrid, TPB, 0, stream>>>(e_dst, counts, ETOT);
  scan_kernel<<<1, TPB, 0, stream>>>(counts, row_ptr, N);
  fill_kernel<<<egrid, TPB, 0, stream>>>(e_src, e_dst, row_ptr, fillc, s_src, ETOT);

  // ---- weight / input conversions (weights transposed for GEMM B) ----
  f32_to_bf16_kernel<<<cgrid(N * 64), TPB, 0, stream>>>(x, xb, N * 64);
  f32_to_bf16_T_kernel<<<dim3(2, 4), 256, 0, stream>>>(Wp, WpT, 64, 128);
  f32_to_bf16_T_kernel<<<dim3(4, 32), 256, 0, stream>>>(W0, W0T, 128, 1024);
  f32_to_bf16_T_kernel<<<dim3(4, 32), 256, 0, stream>>>(W1, W1T, 128, 1024);
  f32_to_bf16_T_kernel<<<dim3(4, 2), 256, 0, stream>>>(W2, W2T, 128, 64);
  f32_to_bf16_T_kernel<<<dim3(4, 2), 256, 0, stream>>>(Wr, WrT, 128, 64);

  // ---- projection: hA = x @ Wp + bp (also bf16 copy hAb) ----
  gemm_bf16t_kernel<<<dim3(mgrid, 1), 256, 0, stream>>>(
      (const short*)xb, (const short*)WpT, bp, hA, hAb, N, 128, 64,
      nullptr, nullptr, nullptr, nullptr, 1, 7);

  // ---- layer 0: GEMM (bf16 out) + fused es/ed ----
  gemm_bf16t_kernel<<<dim3(mgrid, 8), 256, 0, stream>>>(
      (const short*)hAb, (const short*)W0T, nullptr, nullptr, gbufb, N, 1024, 128,
      as0, ad0, es, ed, 8, 7);
  gat_aggregate8w_kernel<<<(N + 3) / 4, 256, 0, stream>>>(
      row_ptr, s_src, (const unsigned short*)gbufb, es, ed, b0, gat, N);
  hipMemsetAsync(bnsum, 0, 2 * 128 * 4, stream);
  bn_stats_kernel<128><<<(N + 127) / 128, 256, 0, stream>>>(gat, N, bnsum);
  bn_elu_res_kernel<128><<<cgrid(N * 128), TPB, 0, stream>>>(gat, bnsum, g0, be0, hA, hB, hBb, N);

  // ---- layer 1 ----
  gemm_bf16t_kernel<<<dim3(mgrid, 8), 256, 0, stream>>>(
      (const short*)hBb, (const short*)W1T, nullptr, nullptr, gbufb, N, 1024, 128,
      as1, ad1, es, ed, 8, 7);
  gat_aggregate8w_kernel<<<(N + 3) / 4, 256, 0, stream>>>(
      row_ptr, s_src, (const unsigned short*)gbufb, es, ed, b1, gat, N);
  hipMemsetAsync(bnsum, 0, 2 * 128 * 4, stream);
  bn_stats_kernel<128><<<(N + 127) / 128, 256, 0, stream>>>(gat, N, bnsum);
  bn_elu_res_kernel<128><<<cgrid(N * 128), TPB, 0, stream>>>(gat, bnsum, g1, be1, hB, hA, hAb, N);

  // ---- layer 2 (H=1, C=64) ----
  gemm_bf16t_kernel<<<dim3(mgrid, 1), 256, 0, stream>>>(
      (const short*)hAb, (const short*)WrT, br, hB, nullptr, N, 64, 128,
      nullptr, nullptr, nullptr, nullptr, 1, 7);    // hr
  gemm_bf16t_kernel<<<dim3(mgrid, 1), 256, 0, stream>>>(
      (const short*)hAb, (const short*)W2T, nullptr, gbuf, nullptr, N, 64, 128,
      as2, ad2, es, ed, 1, 6);
  gat_aggregate1_kernel<<<(N + 3) / 4, 256, 0, stream>>>(row_ptr, s_src, gbuf, es, ed, b2, gat, N);
  hipMemsetAsync(bnsum, 0, 2 * 64 * 4, stream);
  bn_stats_kernel<64><<<(N + 255) / 256, 256, 0, stream>>>(gat, N, bnsum);
  bn_elu_res_kernel<64><<<cgrid(N * 64), TPB, 0, stream>>>(gat, bnsum, g2, be2, hB, (float*)d_out, nullptr, N);
}

// Round 7
// 319.849 us; speedup vs baseline: 1.0658x; 1.0043x over previous
//
#include <hip/hip_runtime.h>
#include <hip/hip_bf16.h>
#include <cstdint>
#include <cstddef>

#define TPB 256

typedef __attribute__((ext_vector_type(8))) short bf16x8;
typedef __attribute__((ext_vector_type(8))) unsigned short ushort8;
typedef __attribute__((ext_vector_type(4))) float f32x4;

static __device__ __forceinline__ float bf2f(unsigned short u) {
  union { unsigned int i; float f; } c;
  c.i = ((unsigned int)u) << 16;
  return c.f;
}

// ---------------------------------------------------------------------------
// Edge dtype detection
// ---------------------------------------------------------------------------
__global__ void detect_kernel(const unsigned int* __restrict__ w, int* __restrict__ flag) {
  __shared__ int any32;
  if (threadIdx.x == 0) any32 = 0;
  __syncthreads();
  for (int i = threadIdx.x; i < 1024; i += TPB)
    if (w[2 * i + 1] != 0u) any32 = 1;
  __syncthreads();
  if (threadIdx.x == 0) *flag = any32;   // 1 -> int32 data, 0 -> int64 data
}

__global__ void decode_kernel(const void* __restrict__ raw, const int* __restrict__ flag,
                              int* __restrict__ src, int* __restrict__ dst, int E, int n) {
  int i = blockIdx.x * TPB + threadIdx.x;
  int tot = E + n;
  if (i >= tot) return;
  if (i < E) {
    if (*flag) {
      const int* p = (const int*)raw;
      src[i] = p[i];
      dst[i] = p[E + i];
    } else {
      const long long* p = (const long long*)raw;
      src[i] = (int)p[i];
      dst[i] = (int)p[E + i];
    }
  } else {
    src[i] = i - E;
    dst[i] = i - E;
  }
}

// ---------------------------------------------------------------------------
// CSR build: count -> scan -> fill
// ---------------------------------------------------------------------------
__global__ void count_kernel(const int* __restrict__ dst, int* __restrict__ counts, int etot) {
  int i = blockIdx.x * TPB + threadIdx.x;
  if (i < etot) atomicAdd(&counts[dst[i]], 1);
}

__global__ void scan_kernel(const int* __restrict__ counts, int* __restrict__ row_ptr, int n) {
  __shared__ int part[TPB];
  int tid = threadIdx.x;
  int chunk = (n + TPB - 1) / TPB;
  int begin = tid * chunk;
  int end = begin + chunk; if (end > n) end = n;
  int s = 0;
  for (int i = begin; i < end && i < n; i++) s += counts[i];
  part[tid] = s;
  __syncthreads();
  for (int off = 1; off < TPB; off <<= 1) {
    int v = (tid >= off) ? part[tid - off] : 0;
    __syncthreads();
    part[tid] += v;
    __syncthreads();
  }
  int base = (tid == 0) ? 0 : part[tid - 1];
  for (int i = begin; i < end && i < n; i++) { row_ptr[i] = base; base += counts[i]; }
  if (tid == TPB - 1) row_ptr[n] = base;
}

__global__ void fill_kernel(const int* __restrict__ src, const int* __restrict__ dst,
                            const int* __restrict__ row_ptr, int* __restrict__ fill,
                            int* __restrict__ sorted_src, int etot) {
  int i = blockIdx.x * TPB + threadIdx.x;
  if (i >= etot) return;
  int d = dst[i];
  int pos = row_ptr[d] + atomicAdd(&fill[d], 1);
  sorted_src[pos] = src[i];
}

// ---------------------------------------------------------------------------
// fp32 -> bf16 convert (linear)
// ---------------------------------------------------------------------------
__global__ void f32_to_bf16_kernel(const float* __restrict__ in, __hip_bfloat16* __restrict__ out, int n) {
  int i = blockIdx.x * TPB + threadIdx.x;
  if (i < n) out[i] = __float2bfloat16(in[i]);
}

// fp32 [K][N] -> bf16 transposed [N][K]
__global__ void f32_to_bf16_T_kernel(const float* __restrict__ in, __hip_bfloat16* __restrict__ out,
                                     int K, int N) {
  __shared__ float tile[32][33];
  const int k0 = blockIdx.x * 32, n0 = blockIdx.y * 32;
  const int tx = threadIdx.x & 31, ty = threadIdx.x >> 5;   // 32 x 8
  for (int r = ty; r < 32; r += 8) {
    int k = k0 + r, n = n0 + tx;
    tile[r][tx] = (k < K && n < N) ? in[(size_t)k * N + n] : 0.f;
  }
  __syncthreads();
  for (int r = ty; r < 32; r += 8) {
    int n = n0 + r, k = k0 + tx;
    if (n < N && k < K) out[(size_t)n * K + k] = __float2bfloat16(tile[tx][r]);
  }
}

// ---------------------------------------------------------------------------
// bf16 MFMA GEMM with pre-transposed B: C[M,N] = A[M,K] @ Bt[N,K]^T (+bias).
// Tile 64(M) x 128(N), BK=32, 4 waves, mfma_f32_16x16x32_bf16.
// Optional fused attention coefficients (es/ed) per head block.
// ---------------------------------------------------------------------------
__global__ __launch_bounds__(256) void gemm_bf16t_kernel(
    const short* __restrict__ A, const short* __restrict__ Bt,
    const float* __restrict__ bias, float* __restrict__ C,
    __hip_bfloat16* __restrict__ Cb, int M, int Ncols, int K,
    const float* __restrict__ asrc, const float* __restrict__ adst,
    float* __restrict__ es_out, float* __restrict__ ed_out, int H, int hshift) {
  __shared__ short As[64][40];    // [row][k], 80B row stride
  __shared__ short Bs[128][40];   // [col][k]

  const int tid = threadIdx.x;
  const int lane = tid & 63;
  const int w = tid >> 6;
  const int bm = blockIdx.x * 64;
  const int bn = blockIdx.y * 128;

  f32x4 acc[8];
#pragma unroll
  for (int nt = 0; nt < 8; nt++) acc[nt] = (f32x4){0.f, 0.f, 0.f, 0.f};

  const int arow = tid >> 2;          // 0..63
  const int akk = (tid & 3) << 3;     // 0,8,16,24
  const int brow = tid >> 1;          // 0..127
  const int bkk = (tid & 1) << 4;     // 0,16

  for (int k0 = 0; k0 < K; k0 += 32) {
    {
      int gr = bm + arow;
      if (gr < M) {
        *(bf16x8*)&As[arow][akk] = *(const bf16x8*)&A[(size_t)gr * K + k0 + akk];
      } else {
        bf16x8 z = {0, 0, 0, 0, 0, 0, 0, 0};
        *(bf16x8*)&As[arow][akk] = z;
      }
    }
    {
      int gbn = bn + brow;
      if (gbn < Ncols) {
        const short* bp = &Bt[(size_t)gbn * K + k0 + bkk];
        *(bf16x8*)&Bs[brow][bkk]     = *(const bf16x8*)bp;
        *(bf16x8*)&Bs[brow][bkk + 8] = *(const bf16x8*)(bp + 8);
      } else {
        bf16x8 z = {0, 0, 0, 0, 0, 0, 0, 0};
        *(bf16x8*)&Bs[brow][bkk] = z;
        *(bf16x8*)&Bs[brow][bkk + 8] = z;
      }
    }
    __syncthreads();

    bf16x8 a = *(const bf16x8*)&As[w * 16 + (lane & 15)][(lane >> 4) * 8];
#pragma unroll
    for (int nt = 0; nt < 8; nt++) {
      bf16x8 b = *(const bf16x8*)&Bs[nt * 16 + (lane & 15)][(lane >> 4) * 8];
      acc[nt] = __builtin_amdgcn_mfma_f32_16x16x32_bf16(a, b, acc[nt], 0, 0, 0);
    }
    __syncthreads();
  }

  float p1[4] = {0.f, 0.f, 0.f, 0.f};
  float p2[4] = {0.f, 0.f, 0.f, 0.f};

#pragma unroll
  for (int nt = 0; nt < 8; nt++) {
    int gc = bn + nt * 16 + (lane & 15);
    if (gc >= Ncols) continue;
    float bv = bias ? bias[gc] : 0.f;
    float asv = es_out ? asrc[gc] : 0.f;
    float adv = es_out ? adst[gc] : 0.f;
#pragma unroll
    for (int q = 0; q < 4; q++) {
      int gr = bm + w * 16 + (lane >> 4) * 4 + q;
      if (gr < M) {
        float val = acc[nt][q] + bv;
        if (C) C[(size_t)gr * Ncols + gc] = val;
        if (Cb) Cb[(size_t)gr * Ncols + gc] = __float2bfloat16(val);
        p1[q] += val * asv;
        p2[q] += val * adv;
      }
    }
  }

  if (es_out) {
    const int head = bn >> hshift;
#pragma unroll
    for (int q = 0; q < 4; q++) {
      float s1 = p1[q], s2 = p2[q];
      s1 += __shfl_xor(s1, 1); s2 += __shfl_xor(s2, 1);
      s1 += __shfl_xor(s1, 2); s2 += __shfl_xor(s2, 2);
      s1 += __shfl_xor(s1, 4); s2 += __shfl_xor(s2, 4);
      s1 += __shfl_xor(s1, 8); s2 += __shfl_xor(s2, 8);
      int gr = bm + w * 16 + (lane >> 4) * 4 + q;
      if ((lane & 15) == 0 && gr < M) {
        es_out[(size_t)gr * H + head] = s1;
        ed_out[(size_t)gr * H + head] = s2;
      }
    }
  }
}

// ---------------------------------------------------------------------------
// Per-dst softmax + aggregation, H=8 C=128, bf16 g.
// TWO WAVES PER NODE: wave w owns heads 4w..4w+3 (512 channels, 8/lane).
// Block = 4 waves = 2 nodes. Alpha phase per wave (lane = edge16 x head4),
// weights to private LDS slice, gather unrolled 8 edges (8 loads in flight,
// padded slots have w=0 / src=0). One barrier for cross-wave head-mean.
// ---------------------------------------------------------------------------
__global__ __launch_bounds__(256) void gat_aggregate8w_kernel(
    const int* __restrict__ row_ptr, const int* __restrict__ srcs,
    const unsigned short* __restrict__ gb, const float* __restrict__ es,
    const float* __restrict__ ed, const float* __restrict__ bias,
    float* __restrict__ out, int n) {
  const int wg = threadIdx.x >> 6;          // wave in block (0..3)
  const int lane = threadIdx.x & 63;
  const int v = blockIdx.x * 2 + (wg >> 1); // node
  const int w = wg & 1;                     // head-half (0: heads 0-3, 1: 4-7)

  __shared__ float wlds[4][64][4];          // [wave][edge][head4]
  __shared__ int slds[4][64];
  __shared__ float plds[4][16][8];          // epilogue partials

  const bool active = (v < n);
  const int begin = active ? row_ptr[v] : 0;
  const int deg = active ? (row_ptr[v + 1] - begin) : 0;

  const int eh4 = lane & 3;                 // head offset in half
  const int ee16 = lane >> 2;               // edge index within 16-sweep
  const int hh4 = lane >> 4;                // gather-phase head offset
  const int c0 = w * 512 + lane * 8;        // channel offset in g row

  const float edv = active ? ed[(size_t)v * 8 + w * 4 + eh4] : 0.f;

  float acc[8];
#pragma unroll
  for (int k = 0; k < 8; k++) acc[k] = 0.f;

  if (active && deg <= 64) {
    // ---- alpha (4 heads of this half), register-resident ----
    float a[4];
    int sreg[4];
#pragma unroll
    for (int b = 0; b < 4; b++) {
      a[b] = -1e30f;
      sreg[b] = 0;
      int e = b * 16 + ee16;
      if (e < deg) {
        int s = srcs[begin + e];
        sreg[b] = s;
        float t = es[(size_t)s * 8 + w * 4 + eh4] + edv;
        a[b] = t > 0.f ? t : 0.2f * t;
      }
    }
    float m = fmaxf(fmaxf(a[0], a[1]), fmaxf(a[2], a[3]));
    m = fmaxf(m, __shfl_xor(m, 4));
    m = fmaxf(m, __shfl_xor(m, 8));
    m = fmaxf(m, __shfl_xor(m, 16));
    m = fmaxf(m, __shfl_xor(m, 32));
    float dsum = 0.f;
#pragma unroll
    for (int b = 0; b < 4; b++) { a[b] = __expf(a[b] - m); dsum += a[b]; }
    dsum += __shfl_xor(dsum, 4);
    dsum += __shfl_xor(dsum, 8);
    dsum += __shfl_xor(dsum, 16);
    dsum += __shfl_xor(dsum, 32);
    const float invd = 1.0f / (dsum + 1e-16f);
#pragma unroll
    for (int b = 0; b < 4; b++) {
      wlds[wg][b * 16 + ee16][eh4] = a[b] * invd;
      if (eh4 == 0) slds[wg][b * 16 + ee16] = sreg[b];
    }

    // ---- gather: 8 edges/group, 8 independent 16B loads ----
#pragma unroll
    for (int g8 = 0; g8 < 8; g8++) {
      const int j0 = g8 * 8;
      if (j0 >= deg) break;
      float w0 = wlds[wg][j0 + 0][hh4], w1 = wlds[wg][j0 + 1][hh4];
      float w2 = wlds[wg][j0 + 2][hh4], w3 = wlds[wg][j0 + 3][hh4];
      float w4 = wlds[wg][j0 + 4][hh4], w5 = wlds[wg][j0 + 5][hh4];
      float w6 = wlds[wg][j0 + 6][hh4], w7 = wlds[wg][j0 + 7][hh4];
      int s0 = slds[wg][j0 + 0], s1 = slds[wg][j0 + 1];
      int s2 = slds[wg][j0 + 2], s3 = slds[wg][j0 + 3];
      int s4 = slds[wg][j0 + 4], s5 = slds[wg][j0 + 5];
      int s6 = slds[wg][j0 + 6], s7 = slds[wg][j0 + 7];
      ushort8 u0 = *(const ushort8*)&gb[(size_t)s0 * 1024 + c0];
      ushort8 u1 = *(const ushort8*)&gb[(size_t)s1 * 1024 + c0];
      ushort8 u2 = *(const ushort8*)&gb[(size_t)s2 * 1024 + c0];
      ushort8 u3 = *(const ushort8*)&gb[(size_t)s3 * 1024 + c0];
      ushort8 u4 = *(const ushort8*)&gb[(size_t)s4 * 1024 + c0];
      ushort8 u5 = *(const ushort8*)&gb[(size_t)s5 * 1024 + c0];
      ushort8 u6 = *(const ushort8*)&gb[(size_t)s6 * 1024 + c0];
      ushort8 u7 = *(const ushort8*)&gb[(size_t)s7 * 1024 + c0];
#pragma unroll
      for (int k = 0; k < 8; k++) {
        float t0 = w0 * bf2f(u0[k]) + w1 * bf2f(u1[k]);
        float t1 = w2 * bf2f(u2[k]) + w3 * bf2f(u3[k]);
        float t2 = w4 * bf2f(u4[k]) + w5 * bf2f(u5[k]);
        float t3 = w6 * bf2f(u6[k]) + w7 * bf2f(u7[k]);
        acc[k] += (t0 + t1) + (t2 + t3);
      }
    }
  } else if (active) {
    // ---- slow path (deg > 64) ----
    float m = -1e30f;
    for (int e = ee16; e < deg; e += 16) {
      int s = srcs[begin + e];
      float t = es[(size_t)s * 8 + w * 4 + eh4] + edv;
      t = t > 0.f ? t : 0.2f * t;
      m = fmaxf(m, t);
    }
    m = fmaxf(m, __shfl_xor(m, 4));
    m = fmaxf(m, __shfl_xor(m, 8));
    m = fmaxf(m, __shfl_xor(m, 16));
    m = fmaxf(m, __shfl_xor(m, 32));
    float dsum = 0.f;
    for (int e = ee16; e < deg; e += 16) {
      int s = srcs[begin + e];
      float t = es[(size_t)s * 8 + w * 4 + eh4] + edv;
      t = t > 0.f ? t : 0.2f * t;
      dsum += __expf(t - m);
    }
    dsum += __shfl_xor(dsum, 4);
    dsum += __shfl_xor(dsum, 8);
    dsum += __shfl_xor(dsum, 16);
    dsum += __shfl_xor(dsum, 32);
    const float invd = 1.0f / (dsum + 1e-16f);

    for (int base = 0; base < deg; base += 64) {
      const int cnt = min(64, deg - base);
#pragma unroll
      for (int b = 0; b < 4; b++) {
        int e = base + b * 16 + ee16;
        float wv = 0.f; int s = 0;
        if (e < deg) {
          s = srcs[begin + e];
          float t = es[(size_t)s * 8 + w * 4 + eh4] + edv;
          t = t > 0.f ? t : 0.2f * t;
          wv = __expf(t - m) * invd;
        }
        wlds[wg][b * 16 + ee16][eh4] = wv;
        if (eh4 == 0) slds[wg][b * 16 + ee16] = s;
      }
#pragma unroll
      for (int g8 = 0; g8 < 8; g8++) {
        const int j0 = g8 * 8;
        if (j0 >= cnt) break;
        float w0 = wlds[wg][j0 + 0][hh4], w1 = wlds[wg][j0 + 1][hh4];
        float w2 = wlds[wg][j0 + 2][hh4], w3 = wlds[wg][j0 + 3][hh4];
        float w4 = wlds[wg][j0 + 4][hh4], w5 = wlds[wg][j0 + 5][hh4];
        float w6 = wlds[wg][j0 + 6][hh4], w7 = wlds[wg][j0 + 7][hh4];
        int s0 = slds[wg][j0 + 0], s1 = slds[wg][j0 + 1];
        int s2 = slds[wg][j0 + 2], s3 = slds[wg][j0 + 3];
        int s4 = slds[wg][j0 + 4], s5 = slds[wg][j0 + 5];
        int s6 = slds[wg][j0 + 6], s7 = slds[wg][j0 + 7];
        ushort8 u0 = *(const ushort8*)&gb[(size_t)s0 * 1024 + c0];
        ushort8 u1 = *(const ushort8*)&gb[(size_t)s1 * 1024 + c0];
        ushort8 u2 = *(const ushort8*)&gb[(size_t)s2 * 1024 + c0];
        ushort8 u3 = *(const ushort8*)&gb[(size_t)s3 * 1024 + c0];
        ushort8 u4 = *(const ushort8*)&gb[(size_t)s4 * 1024 + c0];
        ushort8 u5 = *(const ushort8*)&gb[(size_t)s5 * 1024 + c0];
        ushort8 u6 = *(const ushort8*)&gb[(size_t)s6 * 1024 + c0];
        ushort8 u7 = *(const ushort8*)&gb[(size_t)s7 * 1024 + c0];
#pragma unroll
        for (int k = 0; k < 8; k++) {
          float t0 = w0 * bf2f(u0[k]) + w1 * bf2f(u1[k]);
          float t1 = w2 * bf2f(u2[k]) + w3 * bf2f(u3[k]);
          float t2 = w4 * bf2f(u4[k]) + w5 * bf2f(u5[k]);
          float t3 = w6 * bf2f(u6[k]) + w7 * bf2f(u7[k]);
          acc[k] += (t0 + t1) + (t2 + t3);
        }
      }
    }
  }

  // ---- head-mean within wave (4 heads), cross-wave via LDS ----
#pragma unroll
  for (int k = 0; k < 8; k++) {
    acc[k] += __shfl_xor(acc[k], 16);
    acc[k] += __shfl_xor(acc[k], 32);
  }
  if (lane < 16) {
#pragma unroll
    for (int k = 0; k < 8; k++) plds[wg][lane][k] = acc[k];
  }
  __syncthreads();
  if (active && w == 0 && lane < 16) {
    const int cc = lane * 8;
#pragma unroll
    for (int k = 0; k < 8; k++) {
      float sum = plds[wg][lane][k] + plds[wg + 1][lane][k];
      out[(size_t)v * 128 + cc + k] = sum * 0.125f + bias[cc + k];
    }
  }
}

// ---------------------------------------------------------------------------
// Layer-2 aggregation (H=1, C=64): one WAVE per dst node, 4 nodes/block.
// ---------------------------------------------------------------------------
__global__ __launch_bounds__(256) void gat_aggregate1_kernel(
    const int* __restrict__ row_ptr, const int* __restrict__ srcs,
    const float* __restrict__ g, const float* __restrict__ es,
    const float* __restrict__ ed, const float* __restrict__ bias,
    float* __restrict__ out, int n) {
  const int wave = threadIdx.x >> 6;
  const int lane = threadIdx.x & 63;
  const int v = blockIdx.x * 4 + wave;
  if (v >= n) return;

  const int begin = row_ptr[v];
  const int deg = row_ptr[v + 1] - begin;
  const float edv = ed[v];

  float pm = -1e30f;
  for (int j = lane; j < deg; j += 64) {
    float a = es[srcs[begin + j]] + edv;
    a = a > 0.f ? a : 0.2f * a;
    pm = fmaxf(pm, a);
  }
#pragma unroll
  for (int off = 32; off > 0; off >>= 1) pm = fmaxf(pm, __shfl_xor(pm, off));

  float ps = 0.f;
  for (int j = lane; j < deg; j += 64) {
    float a = es[srcs[begin + j]] + edv;
    a = a > 0.f ? a : 0.2f * a;
    ps += __expf(a - pm);
  }
#pragma unroll
  for (int off = 32; off > 0; off >>= 1) ps += __shfl_xor(ps, off);
  const float invd = 1.0f / (ps + 1e-16f);

  float acc = 0.f;
  for (int base = 0; base < deg; base += 64) {
    int cnt = deg - base; if (cnt > 64) cnt = 64;
    int sv = 0; float wv = 0.f;
    if (lane < cnt) {
      sv = srcs[begin + base + lane];
      float a = es[sv] + edv;
      a = a > 0.f ? a : 0.2f * a;
      wv = __expf(a - pm) * invd;
    }
    for (int j = 0; j < cnt; j++) {
      int s = __shfl(sv, j);
      float wgt = __shfl(wv, j);
      acc += wgt * g[(size_t)s * 64 + lane];
    }
  }
  out[(size_t)v * 64 + lane] = acc + bias[lane];
}

// ---------------------------------------------------------------------------
// BN column stats
// ---------------------------------------------------------------------------
template <int C>
__global__ void bn_stats_kernel(const float* __restrict__ x, int n, float* __restrict__ sums) {
  constexpr int T = 256;
  constexpr int RPI = T / C;
  constexpr int ITER = 64;
  constexpr int ROWS = RPI * ITER;
  int c = threadIdx.x % C;
  int r0 = threadIdx.x / C;
  int rowBase = blockIdx.x * ROWS;
  float s = 0.f, q = 0.f;
  for (int it = 0; it < ITER; ++it) {
    int r = rowBase + it * RPI + r0;
    if (r < n) {
      float v = x[(size_t)r * C + c];
      s += v; q += v * v;
    }
  }
  __shared__ float ls[T], lq[T];
  ls[threadIdx.x] = s; lq[threadIdx.x] = q;
  __syncthreads();
  if (threadIdx.x < C) {
    float ts = 0.f, tq = 0.f;
    for (int r = 0; r < RPI; ++r) { ts += ls[c + r * C]; tq += lq[c + r * C]; }
    atomicAdd(&sums[c], ts);
    atomicAdd(&sums[C + c], tq);
  }
}

// ---------------------------------------------------------------------------
// out = elu(bn(x)) + res ; optional bf16 copy of out
// ---------------------------------------------------------------------------
template <int C>
__global__ void bn_elu_res_kernel(const float* __restrict__ x, const float* __restrict__ sums,
                                  const float* __restrict__ gamma, const float* __restrict__ beta,
                                  const float* __restrict__ res, float* __restrict__ out,
                                  __hip_bfloat16* __restrict__ outb, int n) {
  int i = blockIdx.x * TPB + threadIdx.x;
  if (i >= n * C) return;
  int c = i % C;
  float inv_n = 1.0f / (float)n;
  float mu = sums[c] * inv_n;
  float var = sums[C + c] * inv_n - mu * mu;
  float y = (x[i] - mu) * rsqrtf(var + 1e-5f) * gamma[c] + beta[c];
  y = y > 0.f ? y : expm1f(y);
  y += res[i];
  out[i] = y;
  if (outb) outb[i] = __float2bfloat16(y);
}

// ---------------------------------------------------------------------------
// host launch
// ---------------------------------------------------------------------------
extern "C" void kernel_launch(void* const* d_in, const int* in_sizes, int n_in,
                              void* d_out, int out_size, void* d_ws, size_t ws_size,
                              hipStream_t stream) {
  const float* x   = (const float*)d_in[0];
  const void*  ei  = d_in[1];
  const float* Wp  = (const float*)d_in[2];
  const float* bp  = (const float*)d_in[3];
  const float* W0  = (const float*)d_in[4];
  const float* as0 = (const float*)d_in[5];
  const float* ad0 = (const float*)d_in[6];
  const float* b0  = (const float*)d_in[7];
  const float* g0  = (const float*)d_in[8];
  const float* be0 = (const float*)d_in[9];
  const float* W1  = (const float*)d_in[10];
  const float* as1 = (const float*)d_in[11];
  const float* ad1 = (const float*)d_in[12];
  const float* b1  = (const float*)d_in[13];
  const float* g1  = (const float*)d_in[14];
  const float* be1 = (const float*)d_in[15];
  const float* W2  = (const float*)d_in[16];
  const float* as2 = (const float*)d_in[17];
  const float* ad2 = (const float*)d_in[18];
  const float* b2  = (const float*)d_in[19];
  const float* g2  = (const float*)d_in[20];
  const float* be2 = (const float*)d_in[21];
  const float* Wr  = (const float*)d_in[22];
  const float* br  = (const float*)d_in[23];

  const int N = in_sizes[0] / 64;       // 10000
  const int E = in_sizes[1] / 2;        // 160000
  const int ETOT = E + N;

  char* wsp = (char*)d_ws;
  size_t off = 0;
  auto alloc = [&](size_t bytes) -> void* {
    void* p = wsp + off;
    off += (bytes + 255) & ~(size_t)255;
    return p;
  };
  int*   flag    = (int*)alloc(4);
  int*   e_src   = (int*)alloc((size_t)ETOT * 4);
  int*   e_dst   = (int*)alloc((size_t)ETOT * 4);
  int*   counts  = (int*)alloc((size_t)N * 4);
  int*   fillc   = (int*)alloc((size_t)N * 4);
  int*   row_ptr = (int*)alloc((size_t)(N + 1) * 4);
  int*   s_src   = (int*)alloc((size_t)ETOT * 4);
  float* hA      = (float*)alloc((size_t)N * 128 * 4);
  float* hB      = (float*)alloc((size_t)N * 128 * 4);
  float* gbuf    = (float*)alloc((size_t)N * 64 * 4);       // layer-2 g (f32)
  float* gat     = (float*)alloc((size_t)N * 128 * 4);
  float* es      = (float*)alloc((size_t)N * 8 * 4);
  float* ed      = (float*)alloc((size_t)N * 8 * 4);
  float* bnsum   = (float*)alloc(2 * 128 * 4);
  __hip_bfloat16* gbufb = (__hip_bfloat16*)alloc((size_t)N * 1024 * 2);  // big-layer g (bf16)
  __hip_bfloat16* xb  = (__hip_bfloat16*)alloc((size_t)N * 64 * 2);
  __hip_bfloat16* hAb = (__hip_bfloat16*)alloc((size_t)N * 128 * 2);
  __hip_bfloat16* hBb = (__hip_bfloat16*)alloc((size_t)N * 128 * 2);
  __hip_bfloat16* WpT = (__hip_bfloat16*)alloc((size_t)128 * 64 * 2);   // [128][64]
  __hip_bfloat16* W0T = (__hip_bfloat16*)alloc((size_t)1024 * 128 * 2); // [1024][128]
  __hip_bfloat16* W1T = (__hip_bfloat16*)alloc((size_t)1024 * 128 * 2);
  __hip_bfloat16* W2T = (__hip_bfloat16*)alloc((size_t)64 * 128 * 2);
  __hip_bfloat16* WrT = (__hip_bfloat16*)alloc((size_t)64 * 128 * 2);

  const int egrid = (ETOT + TPB - 1) / TPB;
  const int mgrid = (N + 63) / 64;      // 157
  auto cgrid = [](int n) { return (n + TPB - 1) / TPB; };

  // ---- graph prep ----
  detect_kernel<<<1, TPB, 0, stream>>>((const unsigned int*)ei, flag);
  decode_kernel<<<egrid, TPB, 0, stream>>>(ei, flag, e_src, e_dst, E, N);
  hipMemsetAsync(counts, 0, (size_t)N * 4, stream);
  hipMemsetAsync(fillc, 0, (size_t)N * 4, stream);
  count_kernel<<<egrid, TPB, 0, stream>>>(e_dst, counts, ETOT);
  scan_kernel<<<1, TPB, 0, stream>>>(counts, row_ptr, N);
  fill_kernel<<<egrid, TPB, 0, stream>>>(e_src, e_dst, row_ptr, fillc, s_src, ETOT);

  // ---- weight / input conversions (weights transposed for GEMM B) ----
  f32_to_bf16_kernel<<<cgrid(N * 64), TPB, 0, stream>>>(x, xb, N * 64);
  f32_to_bf16_T_kernel<<<dim3(2, 4), 256, 0, stream>>>(Wp, WpT, 64, 128);
  f32_to_bf16_T_kernel<<<dim3(4, 32), 256, 0, stream>>>(W0, W0T, 128, 1024);
  f32_to_bf16_T_kernel<<<dim3(4, 32), 256, 0, stream>>>(W1, W1T, 128, 1024);
  f32_to_bf16_T_kernel<<<dim3(4, 2), 256, 0, stream>>>(W2, W2T, 128, 64);
  f32_to_bf16_T_kernel<<<dim3(4, 2), 256, 0, stream>>>(Wr, WrT, 128, 64);

  // ---- projection: hA = x @ Wp + bp (also bf16 copy hAb) ----
  gemm_bf16t_kernel<<<dim3(mgrid, 1), 256, 0, stream>>>(
      (const short*)xb, (const short*)WpT, bp, hA, hAb, N, 128, 64,
      nullptr, nullptr, nullptr, nullptr, 1, 7);

  // ---- layer 0: GEMM (bf16 out) + fused es/ed ----
  gemm_bf16t_kernel<<<dim3(mgrid, 8), 256, 0, stream>>>(
      (const short*)hAb, (const short*)W0T, nullptr, nullptr, gbufb, N, 1024, 128,
      as0, ad0, es, ed, 8, 7);
  gat_aggregate8w_kernel<<<(N + 1) / 2, 256, 0, stream>>>(
      row_ptr, s_src, (const unsigned short*)gbufb, es, ed, b0, gat, N);
  hipMemsetAsync(bnsum, 0, 2 * 128 * 4, stream);
  bn_stats_kernel<128><<<(N + 127) / 128, 256, 0, stream>>>(gat, N, bnsum);
  bn_elu_res_kernel<128><<<cgrid(N * 128), TPB, 0, stream>>>(gat, bnsum, g0, be0, hA, hB, hBb, N);

  // ---- layer 1 ----
  gemm_bf16t_kernel<<<dim3(mgrid, 8), 256, 0, stream>>>(
      (const short*)hBb, (const short*)W1T, nullptr, nullptr, gbufb, N, 1024, 128,
      as1, ad1, es, ed, 8, 7);
  gat_aggregate8w_kernel<<<(N + 1) / 2, 256, 0, stream>>>(
      row_ptr, s_src, (const unsigned short*)gbufb, es, ed, b1, gat, N);
  hipMemsetAsync(bnsum, 0, 2 * 128 * 4, stream);
  bn_stats_kernel<128><<<(N + 127) / 128, 256, 0, stream>>>(gat, N, bnsum);
  bn_elu_res_kernel<128><<<cgrid(N * 128), TPB, 0, stream>>>(gat, bnsum, g1, be1, hB, hA, hAb, N);

  // ---- layer 2 (H=1, C=64) ----
  gemm_bf16t_kernel<<<dim3(mgrid, 1), 256, 0, stream>>>(
      (const short*)hAb, (const short*)WrT, br, hB, nullptr, N, 64, 128,
      nullptr, nullptr, nullptr, nullptr, 1, 7);    // hr
  gemm_bf16t_kernel<<<dim3(mgrid, 1), 256, 0, stream>>>(
      (const short*)hAb, (const short*)W2T, nullptr, gbuf, nullptr, N, 64, 128,
      as2, ad2, es, ed, 1, 6);
  gat_aggregate1_kernel<<<(N + 3) / 4, 256, 0, stream>>>(row_ptr, s_src, gbuf, es, ed, b2, gat, N);
  hipMemsetAsync(bnsum, 0, 2 * 64 * 4, stream);
  bn_stats_kernel<64><<<(N + 255) / 256, 256, 0, stream>>>(gat, N, bnsum);
  bn_elu_res_kernel<64><<<cgrid(N * 64), TPB, 0, stream>>>(gat, bnsum, g2, be2, hB, (float*)d_out, nullptr, N);
}